// Round 1
// baseline (2356.000 us; speedup 1.0000x reference)
//
#include <hip/hip_runtime.h>

// Decoder_75720273428908 — transformerCPI decoder, round 6.
// B=16, T=512, S=1024, H=256, NH=8, D=32, PF=512, L=2, A=64.
// Round-6 change: all GEMMs moved to MFMA (v_mfma_f32_16x16x32_bf16) with
// bf16x3 split (hi*hi + hi*lo + lo*hi, fp32 accum; rel err ~2^-16, fp32-safe).
// Inputs/outputs fp32 (proved rounds 1-4 of prior session).
// Out layout (fp32 elems): label[32] @0, pooled[4096] @32, att[67108864] @4128.
//
// WS layout (bytes from d_ws), total 96 MiB:
//   x      @ 0MB   (8MB fp32 [8192,256])
//   sub    @ 8MB   (8MB)
//   qb     @16MB   (8MB)
//   kb     @24MB   (16MB [16384,256])   } ffm_hi @24MB, ffm_lo @32MB alias
//   vb     @40MB   (16MB)               } trg_hi @40MB, trg_lo @41MB alias (pre-loop)
//                                       } nrm @40MB, pld @40MB+32KB alias (post-loop)
//   x_hi   @56MB, x_lo @60MB            (bf16 [8192,256] each)
//   ob_hi  @64MB, ob_lo @68MB
//   src_hi @72MB, src_lo @80MB          (bf16 [16384,256])
//   w_hi   @88MB, w_lo @92MB            (all weights, transposed to [N,K], 3.18MB each)

typedef __bf16 bfrag __attribute__((ext_vector_type(8)));
typedef float f32x4 __attribute__((ext_vector_type(4)));

#define AROWS 8

// ---------------- bf16 split helpers --------------------------------------
__device__ __forceinline__ unsigned short f2bf(float x) {
  unsigned u = __float_as_uint(x);
  u += 0x7fff + ((u >> 16) & 1);            // RNE
  return (unsigned short)(u >> 16);
}
__device__ __forceinline__ float bf2f(unsigned short h) {
  return __uint_as_float((unsigned)h << 16);
}
__device__ __forceinline__ void split2(float x, unsigned short& hi, unsigned short& lo) {
  hi = f2bf(x);
  lo = f2bf(x - bf2f(hi));                  // residual exact in fp32
}

// ---------------- weight transpose+split: W[K,N] -> T{hi,lo}[N,K] ----------
__global__ __launch_bounds__(256) void wsplit(
    const float* __restrict__ W, short* __restrict__ Th, short* __restrict__ Tl,
    int K, int N)
{
  __shared__ float t[32][33];
  const int n0 = blockIdx.x * 32, k0 = blockIdx.y * 32;
  const int tx = threadIdx.x & 31, ty = threadIdx.x >> 5;
#pragma unroll
  for (int p = 0; p < 4; p++)
    t[ty + p * 8][tx] = W[(size_t)(k0 + ty + p * 8) * N + n0 + tx];
  __syncthreads();
#pragma unroll
  for (int p = 0; p < 4; p++) {
    float v = t[tx][ty + p * 8];            // k=k0+tx, n=n0+ty+p*8
    unsigned short hi, lo; split2(v, hi, lo);
    size_t o = (size_t)(n0 + ty + p * 8) * K + k0 + tx;
    Th[o] = (short)hi; Tl[o] = (short)lo;
  }
}

// ---------------- flat split: X fp32 -> Xh,Xl bf16 -------------------------
__global__ __launch_bounds__(256) void xsplit(
    const float* __restrict__ X, short* __restrict__ Xh, short* __restrict__ Xl,
    int n4)
{
  int i = blockIdx.x * 256 + threadIdx.x;
  if (i < n4) {
    float4 v = ((const float4*)X)[i];
    ushort4 h, l;
    split2(v.x, h.x, l.x); split2(v.y, h.y, l.y);
    split2(v.z, h.z, l.z); split2(v.w, h.w, l.w);
    ((ushort4*)Xh)[i] = h; ((ushort4*)Xl)[i] = l;
  }
}

// ---------------- MFMA GEMM: C[M,N] = A[M,K] @ B[K,N] + bias --------------
// A given as pre-split bf16 hi/lo [M,K]; B given as pre-split TRANSPOSED
// bf16 hi/lo [N,K]. bf16x3: hi*hi + hi*lo + lo*hi into fp32 acc.
// BM=BN=64, BK=32, 256 threads = 4 waves (2x2), per-wave 32x32 (2x2 MFMA tiles).
template <bool RELU, bool SPLIT, bool WRITE_C>
__global__ __launch_bounds__(256) void gemm_mfma(
    const short* __restrict__ Ah_g, const short* __restrict__ Al_g,
    const short* __restrict__ Bh_g, const short* __restrict__ Bl_g,
    const float* __restrict__ bias, float* __restrict__ C,
    short* __restrict__ Ch, short* __restrict__ Cl,
    int M, int N, int K)
{
  __shared__ short Ah[64 * 40], Al[64 * 40], Bh[64 * 40], Bl[64 * 40];  // +8 pad
  const int tid = threadIdx.x;
  const int lane = tid & 63, w = tid >> 6;
  const int wm = w & 1, wn = w >> 1;
  const int m0 = blockIdx.x * 64, n0 = blockIdx.y * 64;
  const int srow = tid >> 2, sc4 = tid & 3;      // staging: row, 16B chunk
  const int l15 = lane & 15, l4 = lane >> 4;
  f32x4 acc[2][2] = {};

  for (int k0 = 0; k0 < K; k0 += 32) {
    {  // stage 4 tiles of [64 rows][32 k] bf16; 1 dwordx4 per thread per tile
      const size_t ga = (size_t)(m0 + srow) * K + k0 + sc4 * 8;
      const size_t gb = (size_t)(n0 + srow) * K + k0 + sc4 * 8;
      uint4 va_h = *(const uint4*)(Ah_g + ga);
      uint4 va_l = *(const uint4*)(Al_g + ga);
      uint4 vb_h = *(const uint4*)(Bh_g + gb);
      uint4 vb_l = *(const uint4*)(Bl_g + gb);
      const int so = srow * 40 + sc4 * 8;
      *(uint4*)(Ah + so) = va_h;  *(uint4*)(Al + so) = va_l;
      *(uint4*)(Bh + so) = vb_h;  *(uint4*)(Bl + so) = vb_l;
    }
    __syncthreads();
    bfrag af_h[2], af_l[2], bf_h[2], bf_l[2];
#pragma unroll
    for (int mi = 0; mi < 2; mi++) {
      int r = wm * 32 + mi * 16 + l15;          // A row; k-chunk = l4*8
      af_h[mi] = *(const bfrag*)(Ah + r * 40 + l4 * 8);
      af_l[mi] = *(const bfrag*)(Al + r * 40 + l4 * 8);
    }
#pragma unroll
    for (int ni = 0; ni < 2; ni++) {
      int r = wn * 32 + ni * 16 + l15;          // B col (row of B^T)
      bf_h[ni] = *(const bfrag*)(Bh + r * 40 + l4 * 8);
      bf_l[ni] = *(const bfrag*)(Bl + r * 40 + l4 * 8);
    }
#pragma unroll
    for (int mi = 0; mi < 2; mi++)
#pragma unroll
      for (int ni = 0; ni < 2; ni++) {
        acc[mi][ni] = __builtin_amdgcn_mfma_f32_16x16x32_bf16(af_h[mi], bf_h[ni], acc[mi][ni], 0, 0, 0);
        acc[mi][ni] = __builtin_amdgcn_mfma_f32_16x16x32_bf16(af_h[mi], bf_l[ni], acc[mi][ni], 0, 0, 0);
        acc[mi][ni] = __builtin_amdgcn_mfma_f32_16x16x32_bf16(af_l[mi], bf_h[ni], acc[mi][ni], 0, 0, 0);
      }
    __syncthreads();
  }
  // epilogue: C/D layout col=lane&15, row=(lane>>4)*4+reg  [m89-verified]
#pragma unroll
  for (int mi = 0; mi < 2; mi++)
#pragma unroll
    for (int ni = 0; ni < 2; ni++) {
      const int n = n0 + wn * 32 + ni * 16 + l15;
      const float bv = bias[n];
#pragma unroll
      for (int r = 0; r < 4; r++) {
        const int m = m0 + wm * 32 + mi * 16 + l4 * 4 + r;
        float v = acc[mi][ni][r] + bv;
        if (RELU) v = fmaxf(v, 0.f);
        const size_t o = (size_t)m * N + n;
        if constexpr (WRITE_C) C[o] = v;
        if constexpr (SPLIT) {
          unsigned short hh, ll; split2(v, hh, ll);
          Ch[o] = (short)hh; Cl[o] = (short)ll;
        }
      }
    }
}

// ---------------- Fused attention (per b,h,8 q-rows) — unchanged core ------
// Q,K,V fp32 in [B,T,NH,D] layout. O written as bf16 hi/lo (feeds o-proj GEMM).
__global__ __launch_bounds__(256) void attn_kernel(
    const float* __restrict__ Q, const float* __restrict__ K,
    const float* __restrict__ V, short* __restrict__ Oh, short* __restrict__ Ol,
    float* __restrict__ att_out, int Tq, int Tk, float inv_scale)
{
  extern __shared__ float smem[];
  const int SCP = Tk + 4;
  float* sc = smem;
  float* kv = sc + 8 * SCP;
  float* qs = kv + 2304;
  const int b = blockIdx.z, h = blockIdx.y, q0 = blockIdx.x * AROWS;
  const int tid = threadIdx.x;

  {  // load 8 Q rows
    int r = tid >> 5, d = tid & 31;
    qs[r * 36 + d] = Q[(((size_t)b * Tq + q0 + r) * 8 + h) * 32 + d];
  }
  for (int kt = 0; kt < Tk; kt += 64) {
    for (int i = tid; i < 2048; i += 256) {
      int kk = i >> 5, d = i & 31;
      kv[kk * 36 + d] = K[(((size_t)b * Tk + kt + kk) * 8 + h) * 32 + d];
    }
    __syncthreads();
#pragma unroll
    for (int pp = 0; pp < 2; pp++) {
      int p = tid + pp * 256;
      int r = p & 7, kk = p >> 3;
      const float4* qv = (const float4*)(qs + r * 36);
      const float4* kq = (const float4*)(kv + kk * 36);
      float s = 0.f;
#pragma unroll
      for (int d4 = 0; d4 < 8; d4++) {
        float4 a = qv[d4], bb = kq[d4];
        s += a.x * bb.x + a.y * bb.y + a.z * bb.z + a.w * bb.w;
      }
      sc[r * SCP + kt + kk] = s * inv_scale;
    }
    __syncthreads();
  }
  {  // softmax: 32 threads per row
    int r = tid >> 5, j = tid & 31;
    float m = -1e30f;
    for (int k = j; k < Tk; k += 32) m = fmaxf(m, sc[r * SCP + k]);
    for (int off = 16; off > 0; off >>= 1) m = fmaxf(m, __shfl_xor(m, off, 32));
    float sum = 0.f;
    for (int k = j; k < Tk; k += 32) {
      float e = __expf(sc[r * SCP + k] - m);
      sc[r * SCP + k] = e; sum += e;
    }
    for (int off = 16; off > 0; off >>= 1) sum += __shfl_xor(sum, off, 32);
    float inv = 1.f / sum;
    for (int k = j; k < Tk; k += 32) sc[r * SCP + k] *= inv;
  }
  __syncthreads();
  if (att_out) {
    for (int i = tid; i < AROWS * 1024; i += 256) {
      int r = i >> 10, k = i & 1023;
      att_out[(((size_t)(b * 8 + h) * Tq) + q0 + r) * 1024 + k] = sc[r * SCP + k];
    }
  }
  // O = P @ V
  const int r = tid >> 5, d = tid & 31;
  float acc = 0.f;
  for (int kt = 0; kt < Tk; kt += 64) {
    __syncthreads();
    for (int i = tid; i < 2048; i += 256) {
      int kk = i >> 5, dd = i & 31;
      kv[dd * 68 + kk] = V[(((size_t)b * Tk + kt + kk) * 8 + h) * 32 + dd];
    }
    __syncthreads();
    const float4* pv = (const float4*)(sc + r * SCP + kt);
    const float4* vv = (const float4*)(kv + d * 68);
#pragma unroll
    for (int k4 = 0; k4 < 16; k4++) {
      float4 p = pv[k4], vx = vv[k4];
      acc += p.x * vx.x + p.y * vx.y + p.z * vx.z + p.w * vx.w;
    }
  }
  unsigned short hh, ll; split2(acc, hh, ll);
  const size_t oo = (((size_t)b * Tq + q0 + r) * 8 + h) * 32 + d;
  Oh[oo] = (short)hh; Ol[oo] = (short)ll;
}

// ---------------- residual + LayerNorm (in place on x) + split out --------
__global__ __launch_bounds__(256) void residual_ln(
    float* __restrict__ x, const float* __restrict__ sub,
    const float* __restrict__ g, const float* __restrict__ bi,
    short* __restrict__ xh, short* __restrict__ xl)
{
  __shared__ float red[4];
  const size_t row = blockIdx.x;
  const int tid = threadIdx.x;
  float v = x[row * 256 + tid] + sub[row * 256 + tid];
  float s = v;
  for (int off = 32; off > 0; off >>= 1) s += __shfl_xor(s, off, 64);
  if ((tid & 63) == 0) red[tid >> 6] = s;
  __syncthreads();
  float mean = (red[0] + red[1] + red[2] + red[3]) * (1.f / 256.f);
  float d = v - mean;
  float s2 = d * d;
  for (int off = 32; off > 0; off >>= 1) s2 += __shfl_xor(s2, off, 64);
  __syncthreads();
  if ((tid & 63) == 0) red[tid >> 6] = s2;
  __syncthreads();
  float var = (red[0] + red[1] + red[2] + red[3]) * (1.f / 256.f);
  float y = d * rsqrtf(var + 1e-5f) * g[tid] + bi[tid];
  x[row * 256 + tid] = y;
  unsigned short hh, ll; split2(y, hh, ll);
  xh[row * 256 + tid] = (short)hh;
  xl[row * 256 + tid] = (short)ll;
}

// ---------------- row norms ------------------------------------------------
__global__ __launch_bounds__(256) void row_norm(
    const float* __restrict__ x, float* __restrict__ nrm)
{
  __shared__ float red[4];
  const size_t row = blockIdx.x;
  const int tid = threadIdx.x;
  float v = x[row * 256 + tid];
  float s = v * v;
  for (int off = 32; off > 0; off >>= 1) s += __shfl_xor(s, off, 64);
  if ((tid & 63) == 0) red[tid >> 6] = s;
  __syncthreads();
  if (tid == 0) nrm[row] = sqrtf(red[0] + red[1] + red[2] + red[3]);
}

// ---------------- norm-softmax pooling (one block per batch) ---------------
__global__ __launch_bounds__(256) void pool_kernel(
    const float* __restrict__ x, const float* __restrict__ nrm,
    float* __restrict__ pooled, float* __restrict__ pooled_out)
{
  __shared__ float w[512];
  __shared__ float red[4];
  const int b = blockIdx.x, tid = threadIdx.x;
  float n0 = nrm[b * 512 + tid], n1 = nrm[b * 512 + 256 + tid];
  float lm = fmaxf(n0, n1);
  for (int off = 32; off > 0; off >>= 1) lm = fmaxf(lm, __shfl_xor(lm, off, 64));
  if ((tid & 63) == 0) red[tid >> 6] = lm;
  __syncthreads();
  float m = fmaxf(fmaxf(red[0], red[1]), fmaxf(red[2], red[3]));
  float e0 = __expf(n0 - m), e1 = __expf(n1 - m);
  float ls = e0 + e1;
  for (int off = 32; off > 0; off >>= 1) ls += __shfl_xor(ls, off, 64);
  __syncthreads();
  if ((tid & 63) == 0) red[tid >> 6] = ls;
  __syncthreads();
  float inv = 1.f / (red[0] + red[1] + red[2] + red[3]);
  w[tid] = e0 * inv; w[tid + 256] = e1 * inv;
  __syncthreads();
  float acc = 0.f;
  for (int t = 0; t < 512; t++)
    acc += w[t] * x[((size_t)b * 512 + t) * 256 + tid];
  pooled[b * 256 + tid] = acc;
  pooled_out[b * 256 + tid] = acc;
}

// ---------------- FC head (one block per batch) ----------------------------
__global__ __launch_bounds__(256) void fc_head(
    const float* __restrict__ pooled,
    const float* __restrict__ fc1_w, const float* __restrict__ fc1_b,
    const float* __restrict__ fc2_w, const float* __restrict__ fc2_b,
    float* __restrict__ label_out)
{
  __shared__ float pl[256];
  __shared__ float hid[256];
  const int b = blockIdx.x, tid = threadIdx.x;
  pl[tid] = pooled[b * 256 + tid];
  __syncthreads();
  float acc = fc1_b[tid];
  for (int k = 0; k < 256; k++)
    acc += pl[k] * fc1_w[k * 256 + tid];
  hid[tid] = fmaxf(acc, 0.f);
  __syncthreads();
  if (tid < 2) {
    float s = fc2_b[tid];
    for (int k = 0; k < 256; k++)
      s += hid[k] * fc2_w[k * 2 + tid];
    label_out[b * 2 + tid] = s;
  }
}

extern "C" void kernel_launch(void* const* d_in, const int* in_sizes, int n_in,
                              void* d_out, int out_size, void* d_ws, size_t ws_size,
                              hipStream_t stream)
{
  const float* trg   = (const float*)d_in[0];
  const float* src   = (const float*)d_in[1];
  const float* ft_w  = (const float*)d_in[2];
  const float* ft_b  = (const float*)d_in[3];
  const float* fc1_w = (const float*)d_in[4];
  const float* fc1_b = (const float*)d_in[5];
  const float* fc2_w = (const float*)d_in[6];
  const float* fc2_b = (const float*)d_in[7];
  const float* ln_g  = (const float*)d_in[8];
  const float* ln_b  = (const float*)d_in[9];
  const float* pf_w1 = (const float*)d_in[10];
  const float* pf_b1 = (const float*)d_in[11];
  const float* pf_w2 = (const float*)d_in[12];
  const float* pf_b2 = (const float*)d_in[13];
  const float* aw[2][8];
  for (int p = 0; p < 2; p++)
    for (int i = 0; i < 8; i++) aw[p][i] = (const float*)d_in[14 + p * 8 + i];
  float* outp = (float*)d_out;

  char* wsb = (char*)d_ws;
  const size_t MB = 1u << 20;
  float* x    = (float*)(wsb);
  float* sub  = (float*)(wsb + 8 * MB);
  float* qb   = (float*)(wsb + 16 * MB);
  float* kb   = (float*)(wsb + 24 * MB);
  float* vb   = (float*)(wsb + 40 * MB);
  short* x_hi = (short*)(wsb + 56 * MB);
  short* x_lo = (short*)(wsb + 60 * MB);
  short* obh  = (short*)(wsb + 64 * MB);
  short* obl  = (short*)(wsb + 68 * MB);
  short* srch = (short*)(wsb + 72 * MB);
  short* srcl = (short*)(wsb + 80 * MB);
  short* w_hi = (short*)(wsb + 88 * MB);   // 1,589,248 elems = 3.03 MiB
  short* w_lo = (short*)(wsb + 92 * MB);   // total ws use: 96 MiB
  // aliases with disjoint lifetimes:
  short* ffmh = (short*)kb;                // FFN mid [8192,512] hi (kb free in FFN)
  short* ffml = (short*)(wsb + 32 * MB);   // lo
  short* trgh = (short*)vb;                // pre-loop only
  short* trgl = (short*)(wsb + 41 * MB);
  float* nrm  = vb;                        // post-loop only
  float* pld  = vb + 8192;

  const float inv_scale = 0.17677669529663687f;  // 1/sqrt(32)

  // weight transposed-split offsets (elems): ftT then per-layer
  // [sa q,k,v,o][ea q,k,v,o][pf1T][pf2T]
  auto woff = [](int l, int idx) -> size_t {
    size_t base = 16384 + (size_t)l * 786432;
    if (idx < 8)  return base + (size_t)idx * 65536;
    if (idx == 8) return base + 524288;
    return base + 655360;
  };

  // ---- one-time prep: split weights (transposed) and inputs ----
  wsplit<<<dim3(8, 2), 256, 0, stream>>>(ft_w, w_hi, w_lo, 64, 256);
  for (int l = 0; l < 2; l++) {
    const size_t wo = (size_t)l * 65536;
    for (int i = 0; i < 4; i++)
      wsplit<<<dim3(8, 8), 256, 0, stream>>>(aw[0][2 * i] + wo,
          w_hi + woff(l, i), w_lo + woff(l, i), 256, 256);
    for (int i = 0; i < 4; i++)
      wsplit<<<dim3(8, 8), 256, 0, stream>>>(aw[1][2 * i] + wo,
          w_hi + woff(l, 4 + i), w_lo + woff(l, 4 + i), 256, 256);
    wsplit<<<dim3(16, 8), 256, 0, stream>>>(pf_w1 + (size_t)l * 131072,
        w_hi + woff(l, 8), w_lo + woff(l, 8), 256, 512);
    wsplit<<<dim3(8, 16), 256, 0, stream>>>(pf_w2 + (size_t)l * 131072,
        w_hi + woff(l, 9), w_lo + woff(l, 9), 512, 256);
  }
  xsplit<<<512, 256, 0, stream>>>(trg, trgh, trgl, 131072);     // 8192*64/4
  xsplit<<<4096, 256, 0, stream>>>(src, srch, srcl, 1048576);   // 16384*256/4

  // feature transform: x = trg @ ft_w + ft_b  (also emits x hi/lo)
  gemm_mfma<false, true, true><<<dim3(128, 4), 256, 0, stream>>>(
      trgh, trgl, w_hi, w_lo, ft_b, x, x_hi, x_lo, 8192, 256, 64);

  for (int l = 0; l < 2; l++) {
    const size_t bo = (size_t)l * 256;
    // ---- self attention ----
    gemm_mfma<false, false, true><<<dim3(128, 4), 256, 0, stream>>>(
        x_hi, x_lo, w_hi + woff(l, 0), w_lo + woff(l, 0), aw[0][1] + bo,
        qb, nullptr, nullptr, 8192, 256, 256);
    gemm_mfma<false, false, true><<<dim3(128, 4), 256, 0, stream>>>(
        x_hi, x_lo, w_hi + woff(l, 1), w_lo + woff(l, 1), aw[0][3] + bo,
        kb, nullptr, nullptr, 8192, 256, 256);
    gemm_mfma<false, false, true><<<dim3(128, 4), 256, 0, stream>>>(
        x_hi, x_lo, w_hi + woff(l, 2), w_lo + woff(l, 2), aw[0][5] + bo,
        vb, nullptr, nullptr, 8192, 256, 256);
    {
      size_t sm = (8 * (512 + 4) + 2304 + 288) * sizeof(float);
      attn_kernel<<<dim3(64, 8, 16), 256, sm, stream>>>(
          qb, kb, vb, obh, obl, (float*)nullptr, 512, 512, inv_scale);
    }
    gemm_mfma<false, false, true><<<dim3(128, 4), 256, 0, stream>>>(
        obh, obl, w_hi + woff(l, 3), w_lo + woff(l, 3), aw[0][7] + bo,
        sub, nullptr, nullptr, 8192, 256, 256);
    residual_ln<<<8192, 256, 0, stream>>>(x, sub, ln_g + bo, ln_b + bo, x_hi, x_lo);
    // ---- encoder (cross) attention ----
    gemm_mfma<false, false, true><<<dim3(128, 4), 256, 0, stream>>>(
        x_hi, x_lo, w_hi + woff(l, 4), w_lo + woff(l, 4), aw[1][1] + bo,
        qb, nullptr, nullptr, 8192, 256, 256);
    gemm_mfma<false, false, true><<<dim3(256, 4), 256, 0, stream>>>(
        srch, srcl, w_hi + woff(l, 5), w_lo + woff(l, 5), aw[1][3] + bo,
        kb, nullptr, nullptr, 16384, 256, 256);
    gemm_mfma<false, false, true><<<dim3(256, 4), 256, 0, stream>>>(
        srch, srcl, w_hi + woff(l, 6), w_lo + woff(l, 6), aw[1][5] + bo,
        vb, nullptr, nullptr, 16384, 256, 256);
    {
      size_t sm = (8 * (1024 + 4) + 2304 + 288) * sizeof(float);
      float* att = (l == 1) ? (outp + 4128) : (float*)nullptr;
      attn_kernel<<<dim3(64, 8, 16), 256, sm, stream>>>(
          qb, kb, vb, obh, obl, att, 512, 1024, inv_scale);
    }
    gemm_mfma<false, false, true><<<dim3(128, 4), 256, 0, stream>>>(
        obh, obl, w_hi + woff(l, 7), w_lo + woff(l, 7), aw[1][7] + bo,
        sub, nullptr, nullptr, 8192, 256, 256);
    residual_ln<<<8192, 256, 0, stream>>>(x, sub, ln_g + bo, ln_b + bo, x_hi, x_lo);
    // ---- feed forward ----
    gemm_mfma<true, true, false><<<dim3(128, 8), 256, 0, stream>>>(
        x_hi, x_lo, w_hi + woff(l, 8), w_lo + woff(l, 8), pf_b1 + (size_t)l * 512,
        nullptr, ffmh, ffml, 8192, 512, 256);
    gemm_mfma<false, false, true><<<dim3(128, 4), 256, 0, stream>>>(
        ffmh, ffml, w_hi + woff(l, 9), w_lo + woff(l, 9), pf_b2 + bo,
        sub, nullptr, nullptr, 8192, 256, 512);
    residual_ln<<<8192, 256, 0, stream>>>(x, sub, ln_g + bo, ln_b + bo, x_hi, x_lo);
  }

  // ---- pooling + head ----
  row_norm<<<8192, 256, 0, stream>>>(x, nrm);
  pool_kernel<<<16, 256, 0, stream>>>(x, nrm, pld, outp + 32);
  fc_head<<<16, 256, 0, stream>>>(pld, fc1_w, fc1_b, fc2_w, fc2_b, outp);
}

// Round 2
// 1154.696 us; speedup vs baseline: 2.0404x; 2.0404x over previous
//
#include <hip/hip_runtime.h>

// Decoder_75720273428908 — transformerCPI decoder, round 7.
// B=16, T=512, S=1024, H=256, NH=8, D=32, PF=512, L=2, A=64.
// Round-7 change: attention moved to MFMA (was 2000/2356 us scalar-VALU).
//  - S = QK^T via bf16x3 split MFMA, K fragments direct from global.
//  - S in 64KB LDS, XOR-(row&7) swizzle on 16B groups (row stride = 0 mod 32).
//  - softmax normalize pass eliminated (inv folded into att write + O scale).
//  - PV via MFMA: P split in-reg from LDS, V read from pre-transposed
//    V^T [b,h,d,Tk] bf16 hi/lo written by the V-projection GEMM epilogue.
// Out layout (fp32 elems): label[32] @0, pooled[4096] @32, att[67108864] @4128.
//
// WS layout (MB offsets): x@0(8) sub@8(8) x_hi@16(4) x_lo@20(4) qbh@24(4)
//   qbl@28(4) kbh@32(8) kbl@40(8) vth@48(8) vtl@56(8) obh@64(4) obl@68(4)
//   srch@72(8) srcl@80(8) w_hi@88(3.1) w_lo@92(3.1). Aliases: ffm->kb,
//   trg_split->vt (pre-loop), nrm/pld->qbh (post-loop). Total 96MB.

typedef __bf16 bfrag __attribute__((ext_vector_type(8)));
typedef float f32x4 __attribute__((ext_vector_type(4)));
typedef unsigned int uint4v __attribute__((ext_vector_type(4)));

// ---------------- bf16 split helpers --------------------------------------
__device__ __forceinline__ unsigned short f2bf(float x) {
  unsigned u = __float_as_uint(x);
  u += 0x7fff + ((u >> 16) & 1);            // RNE
  return (unsigned short)(u >> 16);
}
__device__ __forceinline__ float bf2f(unsigned short h) {
  return __uint_as_float((unsigned)h << 16);
}
__device__ __forceinline__ void split2(float x, unsigned short& hi, unsigned short& lo) {
  hi = f2bf(x);
  lo = f2bf(x - bf2f(hi));                  // residual exact in fp32
}

// ---------------- weight transpose+split: W[K,N] -> T{hi,lo}[N,K] ----------
__global__ __launch_bounds__(256) void wsplit(
    const float* __restrict__ W, short* __restrict__ Th, short* __restrict__ Tl,
    int K, int N)
{
  __shared__ float t[32][33];
  const int n0 = blockIdx.x * 32, k0 = blockIdx.y * 32;
  const int tx = threadIdx.x & 31, ty = threadIdx.x >> 5;
#pragma unroll
  for (int p = 0; p < 4; p++)
    t[ty + p * 8][tx] = W[(size_t)(k0 + ty + p * 8) * N + n0 + tx];
  __syncthreads();
#pragma unroll
  for (int p = 0; p < 4; p++) {
    float v = t[tx][ty + p * 8];            // k=k0+tx, n=n0+ty+p*8
    unsigned short hi, lo; split2(v, hi, lo);
    size_t o = (size_t)(n0 + ty + p * 8) * K + k0 + tx;
    Th[o] = (short)hi; Tl[o] = (short)lo;
  }
}

// ---------------- flat split: X fp32 -> Xh,Xl bf16 -------------------------
__global__ __launch_bounds__(256) void xsplit(
    const float* __restrict__ X, short* __restrict__ Xh, short* __restrict__ Xl,
    int n4)
{
  int i = blockIdx.x * 256 + threadIdx.x;
  if (i < n4) {
    float4 v = ((const float4*)X)[i];
    ushort4 h, l;
    split2(v.x, h.x, l.x); split2(v.y, h.y, l.y);
    split2(v.z, h.z, l.z); split2(v.w, h.w, l.w);
    ((ushort4*)Xh)[i] = h; ((ushort4*)Xl)[i] = l;
  }
}

// ---------------- MFMA GEMM: C[M,N] = A[M,K] @ B[K,N] + bias --------------
// A pre-split bf16 hi/lo [M,K]; B pre-split TRANSPOSED bf16 hi/lo [N,K].
// bf16x3: hi*hi + hi*lo + lo*hi into fp32 acc.
// VT mode: write C split into V^T layout [b][h][d][Tk] (Tk = 1<<tksh).
template <bool RELU, bool SPLIT, bool WRITE_C, bool VT>
__global__ __launch_bounds__(256) void gemm_mfma(
    const short* __restrict__ Ah_g, const short* __restrict__ Al_g,
    const short* __restrict__ Bh_g, const short* __restrict__ Bl_g,
    const float* __restrict__ bias, float* __restrict__ C,
    short* __restrict__ Ch, short* __restrict__ Cl,
    int M, int N, int K, int tksh)
{
  __shared__ short Ah[64 * 40], Al[64 * 40], Bh[64 * 40], Bl[64 * 40];  // +8 pad
  const int tid = threadIdx.x;
  const int lane = tid & 63, w = tid >> 6;
  const int wm = w & 1, wn = w >> 1;
  const int m0 = blockIdx.x * 64, n0 = blockIdx.y * 64;
  const int srow = tid >> 2, sc4 = tid & 3;      // staging: row, 16B chunk
  const int l15 = lane & 15, l4 = lane >> 4;
  f32x4 acc[2][2] = {};

  for (int k0 = 0; k0 < K; k0 += 32) {
    {  // stage 4 tiles of [64 rows][32 k] bf16; 1 dwordx4 per thread per tile
      const size_t ga = (size_t)(m0 + srow) * K + k0 + sc4 * 8;
      const size_t gb = (size_t)(n0 + srow) * K + k0 + sc4 * 8;
      uint4 va_h = *(const uint4*)(Ah_g + ga);
      uint4 va_l = *(const uint4*)(Al_g + ga);
      uint4 vb_h = *(const uint4*)(Bh_g + gb);
      uint4 vb_l = *(const uint4*)(Bl_g + gb);
      const int so = srow * 40 + sc4 * 8;
      *(uint4*)(Ah + so) = va_h;  *(uint4*)(Al + so) = va_l;
      *(uint4*)(Bh + so) = vb_h;  *(uint4*)(Bl + so) = vb_l;
    }
    __syncthreads();
    bfrag af_h[2], af_l[2], bf_h[2], bf_l[2];
#pragma unroll
    for (int mi = 0; mi < 2; mi++) {
      int r = wm * 32 + mi * 16 + l15;          // A row; k-chunk = l4*8
      af_h[mi] = *(const bfrag*)(Ah + r * 40 + l4 * 8);
      af_l[mi] = *(const bfrag*)(Al + r * 40 + l4 * 8);
    }
#pragma unroll
    for (int ni = 0; ni < 2; ni++) {
      int r = wn * 32 + ni * 16 + l15;          // B col (row of B^T)
      bf_h[ni] = *(const bfrag*)(Bh + r * 40 + l4 * 8);
      bf_l[ni] = *(const bfrag*)(Bl + r * 40 + l4 * 8);
    }
#pragma unroll
    for (int mi = 0; mi < 2; mi++)
#pragma unroll
      for (int ni = 0; ni < 2; ni++) {
        acc[mi][ni] = __builtin_amdgcn_mfma_f32_16x16x32_bf16(af_h[mi], bf_h[ni], acc[mi][ni], 0, 0, 0);
        acc[mi][ni] = __builtin_amdgcn_mfma_f32_16x16x32_bf16(af_h[mi], bf_l[ni], acc[mi][ni], 0, 0, 0);
        acc[mi][ni] = __builtin_amdgcn_mfma_f32_16x16x32_bf16(af_l[mi], bf_h[ni], acc[mi][ni], 0, 0, 0);
      }
    __syncthreads();
  }
  // epilogue: C/D layout col=lane&15, row=(lane>>4)*4+reg  [m89-verified]
#pragma unroll
  for (int mi = 0; mi < 2; mi++)
#pragma unroll
    for (int ni = 0; ni < 2; ni++) {
      const int n = n0 + wn * 32 + ni * 16 + l15;
      const float bv = bias[n];
      if constexpr (VT) {
        const int m = m0 + wm * 32 + mi * 16 + l4 * 4;
        const int bb = m >> tksh, tt = m & ((1 << tksh) - 1);
        const size_t o = ((((size_t)bb * 8 + (n >> 5)) * 32 + (n & 31)) << tksh) + tt;
        unsigned long long wh = 0, wl = 0;
#pragma unroll
        for (int r = 0; r < 4; r++) {
          float v = acc[mi][ni][r] + bv;
          unsigned short hh, ll; split2(v, hh, ll);
          wh |= (unsigned long long)hh << (16 * r);
          wl |= (unsigned long long)ll << (16 * r);
        }
        *(unsigned long long*)(Ch + o) = wh;
        *(unsigned long long*)(Cl + o) = wl;
      } else {
#pragma unroll
        for (int r = 0; r < 4; r++) {
          const int m = m0 + wm * 32 + mi * 16 + l4 * 4 + r;
          float v = acc[mi][ni][r] + bv;
          if (RELU) v = fmaxf(v, 0.f);
          const size_t o = (size_t)m * N + n;
          if constexpr (WRITE_C) C[o] = v;
          if constexpr (SPLIT) {
            unsigned short hh, ll; split2(v, hh, ll);
            Ch[o] = (short)hh; Cl[o] = (short)ll;
          }
        }
      }
    }
}

// ---------------- MFMA fused attention ------------------------------------
// Per block: 16 q-rows of one (b,h). 4 waves. Q,K in [b,t,h,d] bf16 hi/lo;
// V pre-transposed [b,h,d,Tk] bf16 hi/lo. S in LDS fp32 with XOR-(row&7)
// swizzle on 16B groups. O written bf16 hi/lo (feeds o-proj GEMM).
template <int TK>
__global__ __launch_bounds__(256) void attn_mfma(
    const short* __restrict__ Qh, const short* __restrict__ Ql,
    const short* __restrict__ Kh, const short* __restrict__ Kl,
    const short* __restrict__ Vth, const short* __restrict__ Vtl,
    short* __restrict__ Oh, short* __restrict__ Ol,
    float* __restrict__ att_out)
{
  __shared__ float sc[16 * TK];                 // 64KB (TK=1024) / 32KB (512)
  const int b = blockIdx.z, h = blockIdx.y, q0 = blockIdx.x * 16;
  const int tid = threadIdx.x;
  const int lane = tid & 63, w = tid >> 6;
  const int l15 = lane & 15, l4 = lane >> 4;
  const float inv_scale = 0.17677669529663687f; // 1/sqrt(32)

  // Q fragments (A-operand): row=l15, k-chunk=l4*8 (D=32 exactly one K-pass)
  const size_t qbase = (((size_t)b * 512 + q0 + l15) * 8 + h) * 32 + l4 * 8;
  bfrag qh = *(const bfrag*)(Qh + qbase);
  bfrag ql = *(const bfrag*)(Ql + qbase);

  // ---- phase 1: S = QK^T / sqrt(D); wave w covers cols [w*TK/4, +TK/4) ----
#pragma unroll 4
  for (int t = 0; t < TK / 64; t++) {
    const int n0c = w * (TK / 4) + t * 16;
    const size_t kbase = (((size_t)b * TK + n0c + l15) * 8 + h) * 32 + l4 * 8;
    bfrag kh = *(const bfrag*)(Kh + kbase);
    bfrag kl = *(const bfrag*)(Kl + kbase);
    f32x4 acc = {};
    acc = __builtin_amdgcn_mfma_f32_16x16x32_bf16(qh, kh, acc, 0, 0, 0);
    acc = __builtin_amdgcn_mfma_f32_16x16x32_bf16(qh, kl, acc, 0, 0, 0);
    acc = __builtin_amdgcn_mfma_f32_16x16x32_bf16(ql, kh, acc, 0, 0, 0);
    const int col = n0c + l15;
#pragma unroll
    for (int r = 0; r < 4; r++) {
      const int row = l4 * 4 + r;
      sc[row * TK + ((((col >> 2) ^ (row & 7)) << 2) | (col & 3))] = acc[r] * inv_scale;
    }
  }
  __syncthreads();

  // ---- phase 2: softmax stats; sc := exp(s - m); inv kept in-register ----
  const int sr = tid >> 4, sj = tid & 15, srsw = sr & 7;
  float mx = -1e30f;
  for (int k = sj; k < TK; k += 16)
    mx = fmaxf(mx, sc[sr * TK + ((((k >> 2) ^ srsw) << 2) | (k & 3))]);
#pragma unroll
  for (int off = 8; off > 0; off >>= 1) mx = fmaxf(mx, __shfl_xor(mx, off, 16));
  float sum = 0.f;
  for (int k = sj; k < TK; k += 16) {
    const int idx = sr * TK + ((((k >> 2) ^ srsw) << 2) | (k & 3));
    float e = __expf(sc[idx] - mx);
    sc[idx] = e;
    sum += e;
  }
#pragma unroll
  for (int off = 8; off > 0; off >>= 1) sum += __shfl_xor(sum, off, 16);
  const float inv = 1.f / sum;
  __syncthreads();

  // ---- phase 3: att output (normalized on the fly, coalesced float4) -----
  if (att_out) {
    const size_t orow = (((size_t)(b * 8 + h)) * 512 + q0 + sr) * TK;
    for (int t = 0; t < TK / 64; t++) {
      const int g = sj + 16 * t;
      float4 e4 = *(const float4*)&sc[sr * TK + ((g ^ srsw) << 2)];
      e4.x *= inv; e4.y *= inv; e4.z *= inv; e4.w *= inv;
      *(float4*)&att_out[orow + g * 4] = e4;
    }
  }

  // ---- phase 4: O = P @ V (unnormalized e; scale by inv at the end) ------
  f32x4 oa0 = {}, oa1 = {};
  const float* pr = sc + l15 * TK;
  const int psw = l15 & 7;
  const size_t vb0 = (((size_t)(b * 8 + h)) * 32 + l15) * TK;
  for (int kc = w * (TK / 4); kc < (w + 1) * (TK / 4); kc += 32) {
    const int g0 = (kc >> 2) + l4 * 2;
    float4 p0 = *(const float4*)(pr + ((g0 ^ psw) << 2));
    float4 p1 = *(const float4*)(pr + (((g0 + 1) ^ psw) << 2));
    float f[8] = {p0.x, p0.y, p0.z, p0.w, p1.x, p1.y, p1.z, p1.w};
    uint4v uh, ul;
#pragma unroll
    for (int i = 0; i < 4; i++) {
      unsigned short h0, l0, h1, l1;
      split2(f[2 * i], h0, l0); split2(f[2 * i + 1], h1, l1);
      uh[i] = (unsigned)h0 | ((unsigned)h1 << 16);
      ul[i] = (unsigned)l0 | ((unsigned)l1 << 16);
    }
    bfrag ph = __builtin_bit_cast(bfrag, uh);
    bfrag pl = __builtin_bit_cast(bfrag, ul);
    const size_t vk = vb0 + kc + l4 * 8;
    bfrag v0h = *(const bfrag*)(Vth + vk);
    bfrag v0l = *(const bfrag*)(Vtl + vk);
    bfrag v1h = *(const bfrag*)(Vth + vk + (size_t)16 * TK);
    bfrag v1l = *(const bfrag*)(Vtl + vk + (size_t)16 * TK);
    oa0 = __builtin_amdgcn_mfma_f32_16x16x32_bf16(ph, v0h, oa0, 0, 0, 0);
    oa0 = __builtin_amdgcn_mfma_f32_16x16x32_bf16(ph, v0l, oa0, 0, 0, 0);
    oa0 = __builtin_amdgcn_mfma_f32_16x16x32_bf16(pl, v0h, oa0, 0, 0, 0);
    oa1 = __builtin_amdgcn_mfma_f32_16x16x32_bf16(ph, v1h, oa1, 0, 0, 0);
    oa1 = __builtin_amdgcn_mfma_f32_16x16x32_bf16(ph, v1l, oa1, 0, 0, 0);
    oa1 = __builtin_amdgcn_mfma_f32_16x16x32_bf16(pl, v1h, oa1, 0, 0, 0);
  }
  __syncthreads();               // all reads of sc (P) complete
  float* obuf = sc;              // alias: [4][16][32] partial O
#pragma unroll
  for (int r = 0; r < 4; r++) {
    obuf[(w * 16 + l4 * 4 + r) * 32 + l15]      = oa0[r];
    obuf[(w * 16 + l4 * 4 + r) * 32 + 16 + l15] = oa1[r];
  }
  __syncthreads();
  {  // reduce across waves; thread (q=sr, d=sj / sj+16) holds inv for row sr
    float s0 = 0.f, s1 = 0.f;
#pragma unroll
    for (int ww = 0; ww < 4; ww++) {
      s0 += obuf[(ww * 16 + sr) * 32 + sj];
      s1 += obuf[(ww * 16 + sr) * 32 + 16 + sj];
    }
    s0 *= inv; s1 *= inv;
    unsigned short h0, l0, h1, l1;
    split2(s0, h0, l0); split2(s1, h1, l1);
    const size_t ob = (((size_t)b * 512 + q0 + sr) * 8 + h) * 32 + sj;
    Oh[ob] = (short)h0;      Ol[ob] = (short)l0;
    Oh[ob + 16] = (short)h1; Ol[ob + 16] = (short)l1;
  }
}

// ---------------- residual + LayerNorm (in place on x) + split out --------
__global__ __launch_bounds__(256) void residual_ln(
    float* __restrict__ x, const float* __restrict__ sub,
    const float* __restrict__ g, const float* __restrict__ bi,
    short* __restrict__ xh, short* __restrict__ xl)
{
  __shared__ float red[4];
  const size_t row = blockIdx.x;
  const int tid = threadIdx.x;
  float v = x[row * 256 + tid] + sub[row * 256 + tid];
  float s = v;
  for (int off = 32; off > 0; off >>= 1) s += __shfl_xor(s, off, 64);
  if ((tid & 63) == 0) red[tid >> 6] = s;
  __syncthreads();
  float mean = (red[0] + red[1] + red[2] + red[3]) * (1.f / 256.f);
  float d = v - mean;
  float s2 = d * d;
  for (int off = 32; off > 0; off >>= 1) s2 += __shfl_xor(s2, off, 64);
  __syncthreads();
  if ((tid & 63) == 0) red[tid >> 6] = s2;
  __syncthreads();
  float var = (red[0] + red[1] + red[2] + red[3]) * (1.f / 256.f);
  float y = d * rsqrtf(var + 1e-5f) * g[tid] + bi[tid];
  x[row * 256 + tid] = y;
  unsigned short hh, ll; split2(y, hh, ll);
  xh[row * 256 + tid] = (short)hh;
  xl[row * 256 + tid] = (short)ll;
}

// ---------------- row norms ------------------------------------------------
__global__ __launch_bounds__(256) void row_norm(
    const float* __restrict__ x, float* __restrict__ nrm)
{
  __shared__ float red[4];
  const size_t row = blockIdx.x;
  const int tid = threadIdx.x;
  float v = x[row * 256 + tid];
  float s = v * v;
  for (int off = 32; off > 0; off >>= 1) s += __shfl_xor(s, off, 64);
  if ((tid & 63) == 0) red[tid >> 6] = s;
  __syncthreads();
  if (tid == 0) nrm[row] = sqrtf(red[0] + red[1] + red[2] + red[3]);
}

// ---------------- norm-softmax pooling (one block per batch) ---------------
__global__ __launch_bounds__(256) void pool_kernel(
    const float* __restrict__ x, const float* __restrict__ nrm,
    float* __restrict__ pooled, float* __restrict__ pooled_out)
{
  __shared__ float w[512];
  __shared__ float red[4];
  const int b = blockIdx.x, tid = threadIdx.x;
  float n0 = nrm[b * 512 + tid], n1 = nrm[b * 512 + 256 + tid];
  float lm = fmaxf(n0, n1);
  for (int off = 32; off > 0; off >>= 1) lm = fmaxf(lm, __shfl_xor(lm, off, 64));
  if ((tid & 63) == 0) red[tid >> 6] = lm;
  __syncthreads();
  float m = fmaxf(fmaxf(red[0], red[1]), fmaxf(red[2], red[3]));
  float e0 = __expf(n0 - m), e1 = __expf(n1 - m);
  float ls = e0 + e1;
  for (int off = 32; off > 0; off >>= 1) ls += __shfl_xor(ls, off, 64);
  __syncthreads();
  if ((tid & 63) == 0) red[tid >> 6] = ls;
  __syncthreads();
  float inv = 1.f / (red[0] + red[1] + red[2] + red[3]);
  w[tid] = e0 * inv; w[tid + 256] = e1 * inv;
  __syncthreads();
  float acc = 0.f;
  for (int t = 0; t < 512; t++)
    acc += w[t] * x[((size_t)b * 512 + t) * 256 + tid];
  pooled[b * 256 + tid] = acc;
  pooled_out[b * 256 + tid] = acc;
}

// ---------------- FC head (one block per batch) ----------------------------
__global__ __launch_bounds__(256) void fc_head(
    const float* __restrict__ pooled,
    const float* __restrict__ fc1_w, const float* __restrict__ fc1_b,
    const float* __restrict__ fc2_w, const float* __restrict__ fc2_b,
    float* __restrict__ label_out)
{
  __shared__ float pl[256];
  __shared__ float hid[256];
  const int b = blockIdx.x, tid = threadIdx.x;
  pl[tid] = pooled[b * 256 + tid];
  __syncthreads();
  float acc = fc1_b[tid];
  for (int k = 0; k < 256; k++)
    acc += pl[k] * fc1_w[k * 256 + tid];
  hid[tid] = fmaxf(acc, 0.f);
  __syncthreads();
  if (tid < 2) {
    float s = fc2_b[tid];
    for (int k = 0; k < 256; k++)
      s += hid[k] * fc2_w[k * 2 + tid];
    label_out[b * 2 + tid] = s;
  }
}

extern "C" void kernel_launch(void* const* d_in, const int* in_sizes, int n_in,
                              void* d_out, int out_size, void* d_ws, size_t ws_size,
                              hipStream_t stream)
{
  const float* trg   = (const float*)d_in[0];
  const float* src   = (const float*)d_in[1];
  const float* ft_w  = (const float*)d_in[2];
  const float* ft_b  = (const float*)d_in[3];
  const float* fc1_w = (const float*)d_in[4];
  const float* fc1_b = (const float*)d_in[5];
  const float* fc2_w = (const float*)d_in[6];
  const float* fc2_b = (const float*)d_in[7];
  const float* ln_g  = (const float*)d_in[8];
  const float* ln_b  = (const float*)d_in[9];
  const float* pf_w1 = (const float*)d_in[10];
  const float* pf_b1 = (const float*)d_in[11];
  const float* pf_w2 = (const float*)d_in[12];
  const float* pf_b2 = (const float*)d_in[13];
  const float* aw[2][8];
  for (int p = 0; p < 2; p++)
    for (int i = 0; i < 8; i++) aw[p][i] = (const float*)d_in[14 + p * 8 + i];
  float* outp = (float*)d_out;

  char* wsb = (char*)d_ws;
  const size_t MB = 1u << 20;
  float* x    = (float*)(wsb);
  float* sub  = (float*)(wsb + 8 * MB);
  short* x_hi = (short*)(wsb + 16 * MB);
  short* x_lo = (short*)(wsb + 20 * MB);
  short* qbh  = (short*)(wsb + 24 * MB);
  short* qbl  = (short*)(wsb + 28 * MB);
  short* kbh  = (short*)(wsb + 32 * MB);
  short* kbl  = (short*)(wsb + 40 * MB);
  short* vth  = (short*)(wsb + 48 * MB);
  short* vtl  = (short*)(wsb + 56 * MB);
  short* obh  = (short*)(wsb + 64 * MB);
  short* obl  = (short*)(wsb + 68 * MB);
  short* srch = (short*)(wsb + 72 * MB);
  short* srcl = (short*)(wsb + 80 * MB);
  short* w_hi = (short*)(wsb + 88 * MB);
  short* w_lo = (short*)(wsb + 92 * MB);
  // aliases with disjoint lifetimes:
  short* ffmh = kbh;                 // FFN mid hi (kb dead during FFN)
  short* ffml = kbl;
  short* trgh = vth;                 // pre-loop only
  short* trgl = vtl;
  float* nrm  = (float*)qbh;         // post-loop only
  float* pld  = (float*)qbh + 8192;

  // weight transposed-split offsets (elems): ftT then per-layer
  auto woff = [](int l, int idx) -> size_t {
    size_t base = 16384 + (size_t)l * 786432;
    if (idx < 8)  return base + (size_t)idx * 65536;
    if (idx == 8) return base + 524288;
    return base + 655360;
  };

  // ---- one-time prep: split weights (transposed) and inputs ----
  wsplit<<<dim3(8, 2), 256, 0, stream>>>(ft_w, w_hi, w_lo, 64, 256);
  for (int l = 0; l < 2; l++) {
    const size_t wo = (size_t)l * 65536;
    for (int i = 0; i < 4; i++)
      wsplit<<<dim3(8, 8), 256, 0, stream>>>(aw[0][2 * i] + wo,
          w_hi + woff(l, i), w_lo + woff(l, i), 256, 256);
    for (int i = 0; i < 4; i++)
      wsplit<<<dim3(8, 8), 256, 0, stream>>>(aw[1][2 * i] + wo,
          w_hi + woff(l, 4 + i), w_lo + woff(l, 4 + i), 256, 256);
    wsplit<<<dim3(16, 8), 256, 0, stream>>>(pf_w1 + (size_t)l * 131072,
        w_hi + woff(l, 8), w_lo + woff(l, 8), 256, 512);
    wsplit<<<dim3(8, 16), 256, 0, stream>>>(pf_w2 + (size_t)l * 131072,
        w_hi + woff(l, 9), w_lo + woff(l, 9), 512, 256);
  }
  xsplit<<<512, 256, 0, stream>>>(trg, trgh, trgl, 131072);
  xsplit<<<4096, 256, 0, stream>>>(src, srch, srcl, 1048576);

  // feature transform: x = trg @ ft_w + ft_b  (also emits x hi/lo)
  gemm_mfma<false, true, true, false><<<dim3(128, 4), 256, 0, stream>>>(
      trgh, trgl, w_hi, w_lo, ft_b, x, x_hi, x_lo, 8192, 256, 64, 0);

  for (int l = 0; l < 2; l++) {
    const size_t bo = (size_t)l * 256;
    // ---- self attention ----
    gemm_mfma<false, true, false, false><<<dim3(128, 4), 256, 0, stream>>>(
        x_hi, x_lo, w_hi + woff(l, 0), w_lo + woff(l, 0), aw[0][1] + bo,
        nullptr, qbh, qbl, 8192, 256, 256, 0);
    gemm_mfma<false, true, false, false><<<dim3(128, 4), 256, 0, stream>>>(
        x_hi, x_lo, w_hi + woff(l, 1), w_lo + woff(l, 1), aw[0][3] + bo,
        nullptr, kbh, kbl, 8192, 256, 256, 0);
    gemm_mfma<false, false, false, true><<<dim3(128, 4), 256, 0, stream>>>(
        x_hi, x_lo, w_hi + woff(l, 2), w_lo + woff(l, 2), aw[0][5] + bo,
        nullptr, vth, vtl, 8192, 256, 256, 9);
    attn_mfma<512><<<dim3(32, 8, 16), 256, 0, stream>>>(
        qbh, qbl, kbh, kbl, vth, vtl, obh, obl, (float*)nullptr);
    gemm_mfma<false, false, true, false><<<dim3(128, 4), 256, 0, stream>>>(
        obh, obl, w_hi + woff(l, 3), w_lo + woff(l, 3), aw[0][7] + bo,
        sub, nullptr, nullptr, 8192, 256, 256, 0);
    residual_ln<<<8192, 256, 0, stream>>>(x, sub, ln_g + bo, ln_b + bo, x_hi, x_lo);
    // ---- encoder (cross) attention ----
    gemm_mfma<false, true, false, false><<<dim3(128, 4), 256, 0, stream>>>(
        x_hi, x_lo, w_hi + woff(l, 4), w_lo + woff(l, 4), aw[1][1] + bo,
        nullptr, qbh, qbl, 8192, 256, 256, 0);
    gemm_mfma<false, true, false, false><<<dim3(256, 4), 256, 0, stream>>>(
        srch, srcl, w_hi + woff(l, 5), w_lo + woff(l, 5), aw[1][3] + bo,
        nullptr, kbh, kbl, 16384, 256, 256, 0);
    gemm_mfma<false, false, false, true><<<dim3(256, 4), 256, 0, stream>>>(
        srch, srcl, w_hi + woff(l, 6), w_lo + woff(l, 6), aw[1][5] + bo,
        nullptr, vth, vtl, 16384, 256, 256, 10);
    {
      float* att = (l == 1) ? (outp + 4128) : (float*)nullptr;
      attn_mfma<1024><<<dim3(32, 8, 16), 256, 0, stream>>>(
          qbh, qbl, kbh, kbl, vth, vtl, obh, obl, att);
    }
    gemm_mfma<false, false, true, false><<<dim3(128, 4), 256, 0, stream>>>(
        obh, obl, w_hi + woff(l, 7), w_lo + woff(l, 7), aw[1][7] + bo,
        sub, nullptr, nullptr, 8192, 256, 256, 0);
    residual_ln<<<8192, 256, 0, stream>>>(x, sub, ln_g + bo, ln_b + bo, x_hi, x_lo);
    // ---- feed forward ----
    gemm_mfma<true, true, false, false><<<dim3(128, 8), 256, 0, stream>>>(
        x_hi, x_lo, w_hi + woff(l, 8), w_lo + woff(l, 8), pf_b1 + (size_t)l * 512,
        nullptr, ffmh, ffml, 8192, 512, 256, 0);
    gemm_mfma<false, false, true, false><<<dim3(128, 4), 256, 0, stream>>>(
        ffmh, ffml, w_hi + woff(l, 9), w_lo + woff(l, 9), pf_b2 + bo,
        sub, nullptr, nullptr, 8192, 256, 512, 0);
    residual_ln<<<8192, 256, 0, stream>>>(x, sub, ln_g + bo, ln_b + bo, x_hi, x_lo);
  }

  // ---- pooling + head ----
  row_norm<<<8192, 256, 0, stream>>>(x, nrm);
  pool_kernel<<<16, 256, 0, stream>>>(x, nrm, pld, outp + 32);
  fc_head<<<16, 256, 0, stream>>>(pld, fc1_w, fc1_b, fc2_w, fc2_b, outp);
}

// Round 3
// 1085.215 us; speedup vs baseline: 2.1710x; 1.0640x over previous
//
#include <hip/hip_runtime.h>

// Decoder_75720273428908 — transformerCPI decoder, round 8.
// B=16, T=512, S=1024, H=256, NH=8, D=32, PF=512, L=2, A=64.
// Round-8 changes (attn was latency-bound: occ 21%, all pipes <40%):
//  - attn: 512 threads (8 waves) per block, same 16 q-rows/64KB LDS ->
//    4 waves/SIMD (was 2). Softmax 32 thr/row. 8-way O reduce, stride-33.
//  - attn: XCD-aware 1D grid (n&7 owns 16 (b,h) groups) -> K/V L2-resident
//    per XCD, kills cross-XCD refetch (FETCH 135MB -> ~60MB expected).
//  - QKV (SA) and KV (EA) projections fused into one GEMM launch each
//    (weight rows contiguous in w_hi); last segment writes V^T layout.
// Out layout (fp32 elems): label[32] @0, pooled[4096] @32, att[67108864] @4128.
//
// WS layout (MB offsets): x@0(8) sub@8(8) x_hi@16(4) x_lo@20(4) qbh@24(4)
//   qbl@28(4) kbh@32(8) kbl@40(8) vth@48(8) vtl@56(8) obh@64(4) obl@68(4)
//   srch@72(8) srcl@80(8) w_hi@88(3.1) w_lo@92(3.1). Aliases: ffm->kb,
//   trg_split->vt (pre-loop), nrm/pld->qbh (post-loop). Total 96MB.

typedef __bf16 bfrag __attribute__((ext_vector_type(8)));
typedef float f32x4 __attribute__((ext_vector_type(4)));
typedef unsigned int uint4v __attribute__((ext_vector_type(4)));

// ---------------- bf16 split helpers --------------------------------------
__device__ __forceinline__ unsigned short f2bf(float x) {
  unsigned u = __float_as_uint(x);
  u += 0x7fff + ((u >> 16) & 1);            // RNE
  return (unsigned short)(u >> 16);
}
__device__ __forceinline__ float bf2f(unsigned short h) {
  return __uint_as_float((unsigned)h << 16);
}
__device__ __forceinline__ void split2(float x, unsigned short& hi, unsigned short& lo) {
  hi = f2bf(x);
  lo = f2bf(x - bf2f(hi));                  // residual exact in fp32
}

// ---------------- weight transpose+split: W[K,N] -> T{hi,lo}[N,K] ----------
__global__ __launch_bounds__(256) void wsplit(
    const float* __restrict__ W, short* __restrict__ Th, short* __restrict__ Tl,
    int K, int N)
{
  __shared__ float t[32][33];
  const int n0 = blockIdx.x * 32, k0 = blockIdx.y * 32;
  const int tx = threadIdx.x & 31, ty = threadIdx.x >> 5;
#pragma unroll
  for (int p = 0; p < 4; p++)
    t[ty + p * 8][tx] = W[(size_t)(k0 + ty + p * 8) * N + n0 + tx];
  __syncthreads();
#pragma unroll
  for (int p = 0; p < 4; p++) {
    float v = t[tx][ty + p * 8];            // k=k0+tx, n=n0+ty+p*8
    unsigned short hi, lo; split2(v, hi, lo);
    size_t o = (size_t)(n0 + ty + p * 8) * K + k0 + tx;
    Th[o] = (short)hi; Tl[o] = (short)lo;
  }
}

// ---------------- flat split: X fp32 -> Xh,Xl bf16 -------------------------
__global__ __launch_bounds__(256) void xsplit(
    const float* __restrict__ X, short* __restrict__ Xh, short* __restrict__ Xl,
    int n4)
{
  int i = blockIdx.x * 256 + threadIdx.x;
  if (i < n4) {
    float4 v = ((const float4*)X)[i];
    ushort4 h, l;
    split2(v.x, h.x, l.x); split2(v.y, h.y, l.y);
    split2(v.z, h.z, l.z); split2(v.w, h.w, l.w);
    ((ushort4*)Xh)[i] = h; ((ushort4*)Xl)[i] = l;
  }
}

// ---------------- MFMA GEMM core macro-ish helpers ------------------------
// Shared staging + MFMA body for the 64x64x32 tile, used by both GEMM kernels.
#define GEMM_CORE(Ah_g, Al_g, Bh_g, Bl_g, K)                                   \
  for (int k0 = 0; k0 < K; k0 += 32) {                                         \
    {                                                                          \
      const size_t ga = (size_t)(m0 + srow) * K + k0 + sc4 * 8;                \
      const size_t gb = (size_t)(n0 + srow) * K + k0 + sc4 * 8;                \
      uint4 va_h = *(const uint4*)(Ah_g + ga);                                 \
      uint4 va_l = *(const uint4*)(Al_g + ga);                                 \
      uint4 vb_h = *(const uint4*)(Bh_g + gb);                                 \
      uint4 vb_l = *(const uint4*)(Bl_g + gb);                                 \
      const int so = srow * 40 + sc4 * 8;                                      \
      *(uint4*)(Ah + so) = va_h;  *(uint4*)(Al + so) = va_l;                   \
      *(uint4*)(Bh + so) = vb_h;  *(uint4*)(Bl + so) = vb_l;                   \
    }                                                                          \
    __syncthreads();                                                           \
    bfrag af_h[2], af_l[2], bf_h[2], bf_l[2];                                  \
    _Pragma("unroll")                                                          \
    for (int mi = 0; mi < 2; mi++) {                                           \
      int r = wm * 32 + mi * 16 + l15;                                         \
      af_h[mi] = *(const bfrag*)(Ah + r * 40 + l4 * 8);                        \
      af_l[mi] = *(const bfrag*)(Al + r * 40 + l4 * 8);                        \
    }                                                                          \
    _Pragma("unroll")                                                          \
    for (int ni = 0; ni < 2; ni++) {                                           \
      int r = wn * 32 + ni * 16 + l15;                                         \
      bf_h[ni] = *(const bfrag*)(Bh + r * 40 + l4 * 8);                        \
      bf_l[ni] = *(const bfrag*)(Bl + r * 40 + l4 * 8);                        \
    }                                                                          \
    _Pragma("unroll")                                                          \
    for (int mi = 0; mi < 2; mi++)                                             \
      _Pragma("unroll")                                                        \
      for (int ni = 0; ni < 2; ni++) {                                         \
        acc[mi][ni] = __builtin_amdgcn_mfma_f32_16x16x32_bf16(af_h[mi], bf_h[ni], acc[mi][ni], 0, 0, 0); \
        acc[mi][ni] = __builtin_amdgcn_mfma_f32_16x16x32_bf16(af_h[mi], bf_l[ni], acc[mi][ni], 0, 0, 0); \
        acc[mi][ni] = __builtin_amdgcn_mfma_f32_16x16x32_bf16(af_l[mi], bf_h[ni], acc[mi][ni], 0, 0, 0); \
      }                                                                        \
    __syncthreads();                                                           \
  }

// ---------------- plain MFMA GEMM: C[M,N] = A[M,K] @ B[K,N] + bias --------
template <bool RELU, bool SPLIT, bool WRITE_C>
__global__ __launch_bounds__(256) void gemm_mfma(
    const short* __restrict__ Ah_g, const short* __restrict__ Al_g,
    const short* __restrict__ Bh_g, const short* __restrict__ Bl_g,
    const float* __restrict__ bias, float* __restrict__ C,
    short* __restrict__ Ch, short* __restrict__ Cl,
    int M, int N, int K)
{
  __shared__ short Ah[64 * 40], Al[64 * 40], Bh[64 * 40], Bl[64 * 40];
  const int tid = threadIdx.x;
  const int lane = tid & 63, w = tid >> 6;
  const int wm = w & 1, wn = w >> 1;
  const int m0 = blockIdx.x * 64, n0 = blockIdx.y * 64;
  const int srow = tid >> 2, sc4 = tid & 3;
  const int l15 = lane & 15, l4 = lane >> 4;
  f32x4 acc[2][2] = {};
  GEMM_CORE(Ah_g, Al_g, Bh_g, Bl_g, K)
#pragma unroll
  for (int mi = 0; mi < 2; mi++)
#pragma unroll
    for (int ni = 0; ni < 2; ni++) {
      const int n = n0 + wn * 32 + ni * 16 + l15;
      const float bv = bias[n];
#pragma unroll
      for (int r = 0; r < 4; r++) {
        const int m = m0 + wm * 32 + mi * 16 + l4 * 4 + r;
        float v = acc[mi][ni][r] + bv;
        if (RELU) v = fmaxf(v, 0.f);
        const size_t o = (size_t)m * N + n;
        if constexpr (WRITE_C) C[o] = v;
        if constexpr (SPLIT) {
          unsigned short hh, ll; split2(v, hh, ll);
          Ch[o] = (short)hh; Cl[o] = (short)ll;
        }
      }
    }
}

// ---------------- fused QKV/KV projection GEMM ----------------------------
// B^T rows are nseg consecutive [256,K] weight blocks (q,k,v contiguous in
// w_hi). Segment = n0>>8 (uniform per block). Last segment -> V^T layout
// [b][h][d][1<<tksh]; others -> split bf16 [M,256].
__global__ __launch_bounds__(256) void gemm_qkv(
    const short* __restrict__ Ah_g, const short* __restrict__ Al_g,
    const short* __restrict__ Bh_g, const short* __restrict__ Bl_g,
    const float* __restrict__ b0, const float* __restrict__ b1,
    const float* __restrict__ b2,
    short* __restrict__ D0h, short* __restrict__ D0l,
    short* __restrict__ D1h, short* __restrict__ D1l,
    short* __restrict__ D2h, short* __restrict__ D2l,
    int M, int K, int tksh, int nseg)
{
  __shared__ short Ah[64 * 40], Al[64 * 40], Bh[64 * 40], Bl[64 * 40];
  const int tid = threadIdx.x;
  const int lane = tid & 63, w = tid >> 6;
  const int wm = w & 1, wn = w >> 1;
  const int m0 = blockIdx.x * 64, n0 = blockIdx.y * 64;
  const int srow = tid >> 2, sc4 = tid & 3;
  const int l15 = lane & 15, l4 = lane >> 4;
  f32x4 acc[2][2] = {};
  GEMM_CORE(Ah_g, Al_g, Bh_g, Bl_g, K)
  const int seg = n0 >> 8;
  const bool vt = (seg == nseg - 1);
  const float* bias = (seg == 0) ? b0 : (seg == 1 ? b1 : b2);
  short* Ch = (seg == 0) ? D0h : (seg == 1 ? D1h : D2h);
  short* Cl = (seg == 0) ? D0l : (seg == 1 ? D1l : D2l);
#pragma unroll
  for (int mi = 0; mi < 2; mi++)
#pragma unroll
    for (int ni = 0; ni < 2; ni++) {
      const int n = n0 + wn * 32 + ni * 16 + l15;
      const int nl = n & 255;
      const float bv = bias[nl];
      if (vt) {
        const int m = m0 + wm * 32 + mi * 16 + l4 * 4;
        const int bb = m >> tksh, tt = m & ((1 << tksh) - 1);
        const size_t o = ((((size_t)bb * 8 + (nl >> 5)) * 32 + (nl & 31)) << tksh) + tt;
        unsigned long long wh = 0, wl = 0;
#pragma unroll
        for (int r = 0; r < 4; r++) {
          float v = acc[mi][ni][r] + bv;
          unsigned short hh, ll; split2(v, hh, ll);
          wh |= (unsigned long long)hh << (16 * r);
          wl |= (unsigned long long)ll << (16 * r);
        }
        *(unsigned long long*)(Ch + o) = wh;
        *(unsigned long long*)(Cl + o) = wl;
      } else {
#pragma unroll
        for (int r = 0; r < 4; r++) {
          const int m = m0 + wm * 32 + mi * 16 + l4 * 4 + r;
          float v = acc[mi][ni][r] + bv;
          unsigned short hh, ll; split2(v, hh, ll);
          const size_t o = (size_t)m * 256 + nl;
          Ch[o] = (short)hh; Cl[o] = (short)ll;
        }
      }
    }
}

// ---------------- MFMA fused attention (512 threads, 8 waves) -------------
// Per block: 16 q-rows of one (b,h). Q,K in [b,t,h,d] bf16 hi/lo; V in
// [b,h,d,Tk] bf16 hi/lo. S in LDS fp32, XOR-(row&7) swizzle on 16B groups.
// 1D grid 4096, XCD-aware: n&7 = xcd owns 16 (b,h) groups (K/V L2-resident).
// O written bf16 hi/lo [b,t,h,d].
template <int TK>
__global__ __launch_bounds__(512, 4) void attn_mfma(
    const short* __restrict__ Qh, const short* __restrict__ Ql,
    const short* __restrict__ Kh, const short* __restrict__ Kl,
    const short* __restrict__ Vth, const short* __restrict__ Vtl,
    short* __restrict__ Oh, short* __restrict__ Ol,
    float* __restrict__ att_out)
{
  __shared__ float sc[16 * TK];                 // 64KB (TK=1024) / 32KB (512)
  const int n = blockIdx.x;
  const int xcd = n & 7, ii = n >> 3;
  const int bh = xcd * 16 + (ii >> 5);          // [0,128)
  const int q0 = (ii & 31) * 16;
  const int b = bh >> 3, h = bh & 7;
  const int tid = threadIdx.x;
  const int lane = tid & 63, w = tid >> 6;      // 8 waves
  const int l15 = lane & 15, l4 = lane >> 4;
  const float inv_scale = 0.17677669529663687f; // 1/sqrt(32)

  // Q fragments (A-operand): row=l15, k-chunk=l4*8 (D=32 = one K-pass)
  const size_t qbase = (((size_t)b * 512 + q0 + l15) * 8 + h) * 32 + l4 * 8;
  bfrag qh = *(const bfrag*)(Qh + qbase);
  bfrag ql = *(const bfrag*)(Ql + qbase);

  // ---- phase 1: S = QK^T/sqrt(D); wave w covers cols [w*TK/8, +TK/8) -----
#pragma unroll
  for (int t = 0; t < TK / 128; t++) {
    const int n0c = w * (TK / 8) + t * 16;
    const size_t kbase = (((size_t)b * TK + n0c + l15) * 8 + h) * 32 + l4 * 8;
    bfrag kh = *(const bfrag*)(Kh + kbase);
    bfrag kl = *(const bfrag*)(Kl + kbase);
    f32x4 acc = {};
    acc = __builtin_amdgcn_mfma_f32_16x16x32_bf16(qh, kh, acc, 0, 0, 0);
    acc = __builtin_amdgcn_mfma_f32_16x16x32_bf16(qh, kl, acc, 0, 0, 0);
    acc = __builtin_amdgcn_mfma_f32_16x16x32_bf16(ql, kh, acc, 0, 0, 0);
    const int col = n0c + l15;
#pragma unroll
    for (int r = 0; r < 4; r++) {
      const int row = l4 * 4 + r;
      sc[row * TK + ((((col >> 2) ^ (row & 7)) << 2) | (col & 3))] = acc[r] * inv_scale;
    }
  }
  __syncthreads();

  // ---- phase 2: softmax stats (32 thr/row); sc := exp(s-m); inv in reg ---
  const int sr = tid >> 5, sj = tid & 31, srsw = sr & 7;
  float mx = -1e30f;
  for (int k = sj; k < TK; k += 32)
    mx = fmaxf(mx, sc[sr * TK + ((((k >> 2) ^ srsw) << 2) | (k & 3))]);
#pragma unroll
  for (int off = 16; off > 0; off >>= 1) mx = fmaxf(mx, __shfl_xor(mx, off, 32));
  float sum = 0.f;
  for (int k = sj; k < TK; k += 32) {
    const int idx = sr * TK + ((((k >> 2) ^ srsw) << 2) | (k & 3));
    float e = __expf(sc[idx] - mx);
    sc[idx] = e;
    sum += e;
  }
#pragma unroll
  for (int off = 16; off > 0; off >>= 1) sum += __shfl_xor(sum, off, 32);
  const float inv = 1.f / sum;
  __syncthreads();

  // ---- phase 3: att output (normalized on the fly, coalesced float4) -----
  if (att_out) {
    const size_t orow = (((size_t)(b * 8 + h)) * 512 + q0 + sr) * TK;
#pragma unroll
    for (int t = 0; t < TK / 128; t++) {
      const int g = sj + 32 * t;
      float4 e4 = *(const float4*)&sc[sr * TK + ((g ^ srsw) << 2)];
      e4.x *= inv; e4.y *= inv; e4.z *= inv; e4.w *= inv;
      *(float4*)&att_out[orow + g * 4] = e4;
    }
  }

  // ---- phase 4: O = P @ V (unnormalized e; scale by inv at the end) ------
  f32x4 oa0 = {}, oa1 = {};
  const float* pr = sc + l15 * TK;
  const int psw = l15 & 7;
  const size_t vb0 = (((size_t)(b * 8 + h)) * 32 + l15) * TK;
#pragma unroll
  for (int kc = w * (TK / 8); kc < (w + 1) * (TK / 8); kc += 32) {
    const int g0 = (kc >> 2) + l4 * 2;
    float4 p0 = *(const float4*)(pr + ((g0 ^ psw) << 2));
    float4 p1 = *(const float4*)(pr + (((g0 + 1) ^ psw) << 2));
    float f[8] = {p0.x, p0.y, p0.z, p0.w, p1.x, p1.y, p1.z, p1.w};
    uint4v uh, ul;
#pragma unroll
    for (int i = 0; i < 4; i++) {
      unsigned short h0, l0, h1, l1;
      split2(f[2 * i], h0, l0); split2(f[2 * i + 1], h1, l1);
      uh[i] = (unsigned)h0 | ((unsigned)h1 << 16);
      ul[i] = (unsigned)l0 | ((unsigned)l1 << 16);
    }
    bfrag ph = __builtin_bit_cast(bfrag, uh);
    bfrag pl = __builtin_bit_cast(bfrag, ul);
    const size_t vk = vb0 + kc + l4 * 8;
    bfrag v0h = *(const bfrag*)(Vth + vk);
    bfrag v0l = *(const bfrag*)(Vtl + vk);
    bfrag v1h = *(const bfrag*)(Vth + vk + (size_t)16 * TK);
    bfrag v1l = *(const bfrag*)(Vtl + vk + (size_t)16 * TK);
    oa0 = __builtin_amdgcn_mfma_f32_16x16x32_bf16(ph, v0h, oa0, 0, 0, 0);
    oa0 = __builtin_amdgcn_mfma_f32_16x16x32_bf16(ph, v0l, oa0, 0, 0, 0);
    oa0 = __builtin_amdgcn_mfma_f32_16x16x32_bf16(pl, v0h, oa0, 0, 0, 0);
    oa1 = __builtin_amdgcn_mfma_f32_16x16x32_bf16(ph, v1h, oa1, 0, 0, 0);
    oa1 = __builtin_amdgcn_mfma_f32_16x16x32_bf16(ph, v1l, oa1, 0, 0, 0);
    oa1 = __builtin_amdgcn_mfma_f32_16x16x32_bf16(pl, v1h, oa1, 0, 0, 0);
  }
  __syncthreads();               // all reads of sc (P) complete
  float* obuf = sc;              // alias: [8][16] rows x 33-stride partial O
#pragma unroll
  for (int r = 0; r < 4; r++) {
    obuf[(w * 16 + l4 * 4 + r) * 33 + l15]      = oa0[r];
    obuf[(w * 16 + l4 * 4 + r) * 33 + 16 + l15] = oa1[r];
  }
  __syncthreads();
  {  // reduce across 8 waves; thread (q=sr, d=sj) holds inv for row sr
    float s0 = 0.f;
#pragma unroll
    for (int ww = 0; ww < 8; ww++)
      s0 += obuf[(ww * 16 + sr) * 33 + sj];
    s0 *= inv;
    unsigned short h0, l0;
    split2(s0, h0, l0);
    const size_t ob = (((size_t)b * 512 + q0 + sr) * 8 + h) * 32 + sj;
    Oh[ob] = (short)h0;  Ol[ob] = (short)l0;
  }
}

// ---------------- residual + LayerNorm (in place on x) + split out --------
__global__ __launch_bounds__(256) void residual_ln(
    float* __restrict__ x, const float* __restrict__ sub,
    const float* __restrict__ g, const float* __restrict__ bi,
    short* __restrict__ xh, short* __restrict__ xl)
{
  __shared__ float red[4];
  const size_t row = blockIdx.x;
  const int tid = threadIdx.x;
  float v = x[row * 256 + tid] + sub[row * 256 + tid];
  float s = v;
  for (int off = 32; off > 0; off >>= 1) s += __shfl_xor(s, off, 64);
  if ((tid & 63) == 0) red[tid >> 6] = s;
  __syncthreads();
  float mean = (red[0] + red[1] + red[2] + red[3]) * (1.f / 256.f);
  float d = v - mean;
  float s2 = d * d;
  for (int off = 32; off > 0; off >>= 1) s2 += __shfl_xor(s2, off, 64);
  __syncthreads();
  if ((tid & 63) == 0) red[tid >> 6] = s2;
  __syncthreads();
  float var = (red[0] + red[1] + red[2] + red[3]) * (1.f / 256.f);
  float y = d * rsqrtf(var + 1e-5f) * g[tid] + bi[tid];
  x[row * 256 + tid] = y;
  unsigned short hh, ll; split2(y, hh, ll);
  xh[row * 256 + tid] = (short)hh;
  xl[row * 256 + tid] = (short)ll;
}

// ---------------- row norms ------------------------------------------------
__global__ __launch_bounds__(256) void row_norm(
    const float* __restrict__ x, float* __restrict__ nrm)
{
  __shared__ float red[4];
  const size_t row = blockIdx.x;
  const int tid = threadIdx.x;
  float v = x[row * 256 + tid];
  float s = v * v;
  for (int off = 32; off > 0; off >>= 1) s += __shfl_xor(s, off, 64);
  if ((tid & 63) == 0) red[tid >> 6] = s;
  __syncthreads();
  if (tid == 0) nrm[row] = sqrtf(red[0] + red[1] + red[2] + red[3]);
}

// ---------------- norm-softmax pooling (one block per batch) ---------------
__global__ __launch_bounds__(256) void pool_kernel(
    const float* __restrict__ x, const float* __restrict__ nrm,
    float* __restrict__ pooled, float* __restrict__ pooled_out)
{
  __shared__ float w[512];
  __shared__ float red[4];
  const int b = blockIdx.x, tid = threadIdx.x;
  float n0 = nrm[b * 512 + tid], n1 = nrm[b * 512 + 256 + tid];
  float lm = fmaxf(n0, n1);
  for (int off = 32; off > 0; off >>= 1) lm = fmaxf(lm, __shfl_xor(lm, off, 64));
  if ((tid & 63) == 0) red[tid >> 6] = lm;
  __syncthreads();
  float m = fmaxf(fmaxf(red[0], red[1]), fmaxf(red[2], red[3]));
  float e0 = __expf(n0 - m), e1 = __expf(n1 - m);
  float ls = e0 + e1;
  for (int off = 32; off > 0; off >>= 1) ls += __shfl_xor(ls, off, 64);
  __syncthreads();
  if ((tid & 63) == 0) red[tid >> 6] = ls;
  __syncthreads();
  float inv = 1.f / (red[0] + red[1] + red[2] + red[3]);
  w[tid] = e0 * inv; w[tid + 256] = e1 * inv;
  __syncthreads();
  float acc = 0.f;
  for (int t = 0; t < 512; t++)
    acc += w[t] * x[((size_t)b * 512 + t) * 256 + tid];
  pooled[b * 256 + tid] = acc;
  pooled_out[b * 256 + tid] = acc;
}

// ---------------- FC head (one block per batch) ----------------------------
__global__ __launch_bounds__(256) void fc_head(
    const float* __restrict__ pooled,
    const float* __restrict__ fc1_w, const float* __restrict__ fc1_b,
    const float* __restrict__ fc2_w, const float* __restrict__ fc2_b,
    float* __restrict__ label_out)
{
  __shared__ float pl[256];
  __shared__ float hid[256];
  const int b = blockIdx.x, tid = threadIdx.x;
  pl[tid] = pooled[b * 256 + tid];
  __syncthreads();
  float acc = fc1_b[tid];
  for (int k = 0; k < 256; k++)
    acc += pl[k] * fc1_w[k * 256 + tid];
  hid[tid] = fmaxf(acc, 0.f);
  __syncthreads();
  if (tid < 2) {
    float s = fc2_b[tid];
    for (int k = 0; k < 256; k++)
      s += hid[k] * fc2_w[k * 2 + tid];
    label_out[b * 2 + tid] = s;
  }
}

extern "C" void kernel_launch(void* const* d_in, const int* in_sizes, int n_in,
                              void* d_out, int out_size, void* d_ws, size_t ws_size,
                              hipStream_t stream)
{
  const float* trg   = (const float*)d_in[0];
  const float* src   = (const float*)d_in[1];
  const float* ft_w  = (const float*)d_in[2];
  const float* ft_b  = (const float*)d_in[3];
  const float* fc1_w = (const float*)d_in[4];
  const float* fc1_b = (const float*)d_in[5];
  const float* fc2_w = (const float*)d_in[6];
  const float* fc2_b = (const float*)d_in[7];
  const float* ln_g  = (const float*)d_in[8];
  const float* ln_b  = (const float*)d_in[9];
  const float* pf_w1 = (const float*)d_in[10];
  const float* pf_b1 = (const float*)d_in[11];
  const float* pf_w2 = (const float*)d_in[12];
  const float* pf_b2 = (const float*)d_in[13];
  const float* aw[2][8];
  for (int p = 0; p < 2; p++)
    for (int i = 0; i < 8; i++) aw[p][i] = (const float*)d_in[14 + p * 8 + i];
  float* outp = (float*)d_out;

  char* wsb = (char*)d_ws;
  const size_t MB = 1u << 20;
  float* x    = (float*)(wsb);
  float* sub  = (float*)(wsb + 8 * MB);
  short* x_hi = (short*)(wsb + 16 * MB);
  short* x_lo = (short*)(wsb + 20 * MB);
  short* qbh  = (short*)(wsb + 24 * MB);
  short* qbl  = (short*)(wsb + 28 * MB);
  short* kbh  = (short*)(wsb + 32 * MB);
  short* kbl  = (short*)(wsb + 40 * MB);
  short* vth  = (short*)(wsb + 48 * MB);
  short* vtl  = (short*)(wsb + 56 * MB);
  short* obh  = (short*)(wsb + 64 * MB);
  short* obl  = (short*)(wsb + 68 * MB);
  short* srch = (short*)(wsb + 72 * MB);
  short* srcl = (short*)(wsb + 80 * MB);
  short* w_hi = (short*)(wsb + 88 * MB);
  short* w_lo = (short*)(wsb + 92 * MB);
  // aliases with disjoint lifetimes:
  short* ffmh = kbh;                 // FFN mid hi (kb dead during FFN)
  short* ffml = kbl;
  short* trgh = vth;                 // pre-loop only
  short* trgl = vtl;
  float* nrm  = (float*)qbh;         // post-loop only
  float* pld  = (float*)qbh + 8192;

  // weight transposed-split offsets (elems): ftT then per-layer
  auto woff = [](int l, int idx) -> size_t {
    size_t base = 16384 + (size_t)l * 786432;
    if (idx < 8)  return base + (size_t)idx * 65536;
    if (idx == 8) return base + 524288;
    return base + 655360;
  };

  // ---- one-time prep: split weights (transposed) and inputs ----
  wsplit<<<dim3(8, 2), 256, 0, stream>>>(ft_w, w_hi, w_lo, 64, 256);
  for (int l = 0; l < 2; l++) {
    const size_t wo = (size_t)l * 65536;
    for (int i = 0; i < 4; i++)
      wsplit<<<dim3(8, 8), 256, 0, stream>>>(aw[0][2 * i] + wo,
          w_hi + woff(l, i), w_lo + woff(l, i), 256, 256);
    for (int i = 0; i < 4; i++)
      wsplit<<<dim3(8, 8), 256, 0, stream>>>(aw[1][2 * i] + wo,
          w_hi + woff(l, 4 + i), w_lo + woff(l, 4 + i), 256, 256);
    wsplit<<<dim3(16, 8), 256, 0, stream>>>(pf_w1 + (size_t)l * 131072,
        w_hi + woff(l, 8), w_lo + woff(l, 8), 256, 512);
    wsplit<<<dim3(8, 16), 256, 0, stream>>>(pf_w2 + (size_t)l * 131072,
        w_hi + woff(l, 9), w_lo + woff(l, 9), 512, 256);
  }
  xsplit<<<512, 256, 0, stream>>>(trg, trgh, trgl, 131072);
  xsplit<<<4096, 256, 0, stream>>>(src, srch, srcl, 1048576);

  // feature transform: x = trg @ ft_w + ft_b  (also emits x hi/lo)
  gemm_mfma<false, true, true><<<dim3(128, 4), 256, 0, stream>>>(
      trgh, trgl, w_hi, w_lo, ft_b, x, x_hi, x_lo, 8192, 256, 64);

  for (int l = 0; l < 2; l++) {
    const size_t bo = (size_t)l * 256;
    // ---- self attention: fused QKV projection (1 launch) ----
    gemm_qkv<<<dim3(128, 12), 256, 0, stream>>>(
        x_hi, x_lo, w_hi + woff(l, 0), w_lo + woff(l, 0),
        aw[0][1] + bo, aw[0][3] + bo, aw[0][5] + bo,
        qbh, qbl, kbh, kbl, vth, vtl, 8192, 256, 9, 3);
    attn_mfma<512><<<4096, 512, 0, stream>>>(
        qbh, qbl, kbh, kbl, vth, vtl, obh, obl, (float*)nullptr);
    gemm_mfma<false, false, true><<<dim3(128, 4), 256, 0, stream>>>(
        obh, obl, w_hi + woff(l, 3), w_lo + woff(l, 3), aw[0][7] + bo,
        sub, nullptr, nullptr, 8192, 256, 256);
    residual_ln<<<8192, 256, 0, stream>>>(x, sub, ln_g + bo, ln_b + bo, x_hi, x_lo);
    // ---- encoder (cross) attention: Q from x; fused KV from src ----
    gemm_mfma<false, true, false><<<dim3(128, 4), 256, 0, stream>>>(
        x_hi, x_lo, w_hi + woff(l, 4), w_lo + woff(l, 4), aw[1][1] + bo,
        nullptr, qbh, qbl, 8192, 256, 256);
    gemm_qkv<<<dim3(256, 8), 256, 0, stream>>>(
        srch, srcl, w_hi + woff(l, 5), w_lo + woff(l, 5),
        aw[1][3] + bo, aw[1][5] + bo, nullptr,
        kbh, kbl, vth, vtl, nullptr, nullptr, 16384, 256, 10, 2);
    {
      float* att = (l == 1) ? (outp + 4128) : (float*)nullptr;
      attn_mfma<1024><<<4096, 512, 0, stream>>>(
          qbh, qbl, kbh, kbl, vth, vtl, obh, obl, att);
    }
    gemm_mfma<false, false, true><<<dim3(128, 4), 256, 0, stream>>>(
        obh, obl, w_hi + woff(l, 7), w_lo + woff(l, 7), aw[1][7] + bo,
        sub, nullptr, nullptr, 8192, 256, 256);
    residual_ln<<<8192, 256, 0, stream>>>(x, sub, ln_g + bo, ln_b + bo, x_hi, x_lo);
    // ---- feed forward ----
    gemm_mfma<true, true, false><<<dim3(128, 8), 256, 0, stream>>>(
        x_hi, x_lo, w_hi + woff(l, 8), w_lo + woff(l, 8), pf_b1 + (size_t)l * 512,
        nullptr, ffmh, ffml, 8192, 512, 256);
    gemm_mfma<false, false, true><<<dim3(128, 4), 256, 0, stream>>>(
        ffmh, ffml, w_hi + woff(l, 9), w_lo + woff(l, 9), pf_b2 + bo,
        sub, nullptr, nullptr, 8192, 256, 512);
    residual_ln<<<8192, 256, 0, stream>>>(x, sub, ln_g + bo, ln_b + bo, x_hi, x_lo);
  }

  // ---- pooling + head ----
  row_norm<<<8192, 256, 0, stream>>>(x, nrm);
  pool_kernel<<<16, 256, 0, stream>>>(x, nrm, pld, outp + 32);
  fc_head<<<16, 256, 0, stream>>>(pld, fc1_w, fc1_b, fc2_w, fc2_b, outp);
}

// Round 5
// 1068.319 us; speedup vs baseline: 2.2053x; 1.0158x over previous
//
#include <hip/hip_runtime.h>

// Decoder_75720273428908 — transformerCPI decoder, round 9 (resubmit; round-4
// bench was an infra container failure, no counters).
// B=16, T=512, S=1024, H=256, NH=8, D=32, PF=512, L=2, A=64.
// Round-9 changes (GEMM fleet + launch overhead):
//  - GEMMs: 128x128 tile, BK=32, global_load_lds width-16 staging (m97
//    pattern), 4 waves, 4x4 fragments/wave. ~2.2x over 64^2 structure.
//  - all 21 wsplit launches fused into one wsplit_all (descriptor table).
//  - residual_ln: wave-per-row, barrier-free, float4; WNORM variant emits
//    row norms on the last call (row_norm kernel deleted).
//  - pool split into pool1 (4-way row chunks) + pool2 reduce.
//  - attn unchanged from round 8 (XCD-swizzled, 512 threads).
// Out layout (fp32 elems): label[32] @0, pooled[4096] @32, att[67108864] @4128.
//
// WS layout (MB offsets): x@0(8) sub@8(8) x_hi@16(4) x_lo@20(4) qbh@24(4)
//   qbl@28(4) kbh@32(8) kbl@40(8) vth@48(8) vtl@56(8) obh@64(4) obl@68(4)
//   srch@72(8) srcl@80(8) w_hi@88(3.1) w_lo@92(3.1). Aliases: ffm->kb,
//   trg_split->vt (pre-loop); nrm/pld/partial->qbh (post-loop). Total 96MB.

typedef __bf16 bfrag __attribute__((ext_vector_type(8)));
typedef float f32x4 __attribute__((ext_vector_type(4)));
typedef unsigned int uint4v __attribute__((ext_vector_type(4)));

// ---------------- bf16 split helpers --------------------------------------
__device__ __forceinline__ unsigned short f2bf(float x) {
  unsigned u = __float_as_uint(x);
  u += 0x7fff + ((u >> 16) & 1);            // RNE
  return (unsigned short)(u >> 16);
}
__device__ __forceinline__ float bf2f(unsigned short h) {
  return __uint_as_float((unsigned)h << 16);
}
__device__ __forceinline__ void split2(float x, unsigned short& hi, unsigned short& lo) {
  hi = f2bf(x);
  lo = f2bf(x - bf2f(hi));                  // residual exact in fp32
}

// ---------------- async global->LDS 16B -----------------------------------
__device__ __forceinline__ void load16_lds(const short* g, short* l) {
  __builtin_amdgcn_global_load_lds(
      (const __attribute__((address_space(1))) unsigned int*)g,
      (__attribute__((address_space(3))) unsigned int*)l, 16, 0, 0);
}

// ---------------- fused weight transpose+split (all weights, one launch) ---
struct WDesc { const float* src; long long dst; int K; int N; int tile0; int pad; };
struct WAll { WDesc d[21]; };

__global__ __launch_bounds__(256) void wsplit_all(
    WAll P, short* __restrict__ Th, short* __restrict__ Tl)
{
  __shared__ float t[32][33];
  const int bid = blockIdx.x;
  int i = 0;
  while (i < 20 && bid >= P.d[i + 1].tile0) i++;   // uniform per block
  const float* __restrict__ W = P.d[i].src;
  const int K = P.d[i].K, N = P.d[i].N;
  const int lt = bid - P.d[i].tile0;
  const int ntn = N >> 5;
  const int n0 = (lt % ntn) * 32, k0 = (lt / ntn) * 32;
  short* th = Th + P.d[i].dst;
  short* tl = Tl + P.d[i].dst;
  const int tx = threadIdx.x & 31, ty = threadIdx.x >> 5;
#pragma unroll
  for (int p = 0; p < 4; p++)
    t[ty + p * 8][tx] = W[(size_t)(k0 + ty + p * 8) * N + n0 + tx];
  __syncthreads();
#pragma unroll
  for (int p = 0; p < 4; p++) {
    float v = t[tx][ty + p * 8];            // k=k0+tx, n=n0+ty+p*8
    unsigned short hi, lo; split2(v, hi, lo);
    size_t o = (size_t)(n0 + ty + p * 8) * K + k0 + tx;
    th[o] = (short)hi; tl[o] = (short)lo;
  }
}

// ---------------- flat split: X fp32 -> Xh,Xl bf16 -------------------------
__global__ __launch_bounds__(256) void xsplit(
    const float* __restrict__ X, short* __restrict__ Xh, short* __restrict__ Xl,
    int n4)
{
  int i = blockIdx.x * 256 + threadIdx.x;
  if (i < n4) {
    float4 v = ((const float4*)X)[i];
    ushort4 h, l;
    split2(v.x, h.x, l.x); split2(v.y, h.y, l.y);
    split2(v.z, h.z, l.z); split2(v.w, h.w, l.w);
    ((ushort4*)Xh)[i] = h; ((ushort4*)Xl)[i] = l;
  }
}

// ---------------- GEMM core: 128x128 tile, BK=32, gload_lds staging -------
// LDS linear [row][k] 64B rows; staging: wave w, issue i -> rows i*64+w*16..+15.
// Fragments: A row = wm*64+mi*16+l15, B row (col) = wn*64+ni*16+l15, k=l4*8.
#define GEMM128_CORE(Ah_g, Al_g, Bh_g, Bl_g, K)                                \
  for (int k0 = 0; k0 < K; k0 += 32) {                                         \
    _Pragma("unroll")                                                          \
    for (int i = 0; i < 2; i++) {                                              \
      const int row = i * 64 + w * 16 + srow;                                  \
      const size_t ga = (size_t)(m0 + row) * K + k0 + sc4 * 8;                 \
      const size_t gb = (size_t)(n0 + row) * K + k0 + sc4 * 8;                 \
      const int ldst = i * 2048 + w * 512;                                     \
      load16_lds(Ah_g + ga, &Asl[0][ldst]);                                    \
      load16_lds(Al_g + ga, &Asl[1][ldst]);                                    \
      load16_lds(Bh_g + gb, &Bsl[0][ldst]);                                    \
      load16_lds(Bl_g + gb, &Bsl[1][ldst]);                                    \
    }                                                                          \
    __syncthreads();                                                           \
    bfrag afh[4], afl[4], bfh[4], bfl[4];                                      \
    _Pragma("unroll")                                                          \
    for (int mi = 0; mi < 4; mi++) {                                           \
      const int r = wm * 64 + mi * 16 + l15;                                   \
      afh[mi] = *(const bfrag*)(&Asl[0][r * 32 + l4 * 8]);                     \
      afl[mi] = *(const bfrag*)(&Asl[1][r * 32 + l4 * 8]);                     \
    }                                                                          \
    _Pragma("unroll")                                                          \
    for (int ni = 0; ni < 4; ni++) {                                           \
      const int r = wn * 64 + ni * 16 + l15;                                   \
      bfh[ni] = *(const bfrag*)(&Bsl[0][r * 32 + l4 * 8]);                     \
      bfl[ni] = *(const bfrag*)(&Bsl[1][r * 32 + l4 * 8]);                     \
    }                                                                          \
    _Pragma("unroll")                                                          \
    for (int mi = 0; mi < 4; mi++)                                             \
      _Pragma("unroll")                                                        \
      for (int ni = 0; ni < 4; ni++) {                                         \
        acc[mi][ni] = __builtin_amdgcn_mfma_f32_16x16x32_bf16(afh[mi], bfh[ni], acc[mi][ni], 0, 0, 0); \
        acc[mi][ni] = __builtin_amdgcn_mfma_f32_16x16x32_bf16(afh[mi], bfl[ni], acc[mi][ni], 0, 0, 0); \
        acc[mi][ni] = __builtin_amdgcn_mfma_f32_16x16x32_bf16(afl[mi], bfh[ni], acc[mi][ni], 0, 0, 0); \
      }                                                                        \
    __syncthreads();                                                           \
  }

// ---------------- plain MFMA GEMM: C[M,N] = A[M,K] @ B[K,N] + bias --------
template <bool RELU, bool SPLIT, bool WRITE_C>
__global__ __launch_bounds__(256) void gemm_mfma(
    const short* __restrict__ Ah_g, const short* __restrict__ Al_g,
    const short* __restrict__ Bh_g, const short* __restrict__ Bl_g,
    const float* __restrict__ bias, float* __restrict__ C,
    short* __restrict__ Ch, short* __restrict__ Cl,
    int M, int N, int K)
{
  __shared__ short Asl[2][128 * 32];
  __shared__ short Bsl[2][128 * 32];
  const int tid = threadIdx.x;
  const int lane = tid & 63, w = tid >> 6;
  const int wm = w & 1, wn = w >> 1;
  const int m0 = blockIdx.x * 128, n0 = blockIdx.y * 128;
  const int srow = lane >> 2, sc4 = lane & 3;
  const int l15 = lane & 15, l4 = lane >> 4;
  f32x4 acc[4][4] = {};
  GEMM128_CORE(Ah_g, Al_g, Bh_g, Bl_g, K)
#pragma unroll
  for (int mi = 0; mi < 4; mi++)
#pragma unroll
    for (int ni = 0; ni < 4; ni++) {
      const int n = n0 + wn * 64 + ni * 16 + l15;
      const float bv = bias[n];
#pragma unroll
      for (int r = 0; r < 4; r++) {
        const int m = m0 + wm * 64 + mi * 16 + l4 * 4 + r;
        float v = acc[mi][ni][r] + bv;
        if (RELU) v = fmaxf(v, 0.f);
        const size_t o = (size_t)m * N + n;
        if constexpr (WRITE_C) C[o] = v;
        if constexpr (SPLIT) {
          unsigned short hh, ll; split2(v, hh, ll);
          Ch[o] = (short)hh; Cl[o] = (short)ll;
        }
      }
    }
}

// ---------------- fused QKV/KV projection GEMM ----------------------------
// B^T rows: nseg consecutive [256,K] weight blocks. Segment = n0>>8 (uniform
// per block, 128 | 256). Last segment -> V^T layout [b][h][d][1<<tksh];
// others -> split bf16 [M,256].
__global__ __launch_bounds__(256) void gemm_qkv(
    const short* __restrict__ Ah_g, const short* __restrict__ Al_g,
    const short* __restrict__ Bh_g, const short* __restrict__ Bl_g,
    const float* __restrict__ b0, const float* __restrict__ b1,
    const float* __restrict__ b2,
    short* __restrict__ D0h, short* __restrict__ D0l,
    short* __restrict__ D1h, short* __restrict__ D1l,
    short* __restrict__ D2h, short* __restrict__ D2l,
    int M, int K, int tksh, int nseg)
{
  __shared__ short Asl[2][128 * 32];
  __shared__ short Bsl[2][128 * 32];
  const int tid = threadIdx.x;
  const int lane = tid & 63, w = tid >> 6;
  const int wm = w & 1, wn = w >> 1;
  const int m0 = blockIdx.x * 128, n0 = blockIdx.y * 128;
  const int srow = lane >> 2, sc4 = lane & 3;
  const int l15 = lane & 15, l4 = lane >> 4;
  f32x4 acc[4][4] = {};
  GEMM128_CORE(Ah_g, Al_g, Bh_g, Bl_g, K)
  const int seg = n0 >> 8;
  const bool vt = (seg == nseg - 1);
  const float* bias = (seg == 0) ? b0 : (seg == 1 ? b1 : b2);
  short* Ch = (seg == 0) ? D0h : (seg == 1 ? D1h : D2h);
  short* Cl = (seg == 0) ? D0l : (seg == 1 ? D1l : D2l);
#pragma unroll
  for (int mi = 0; mi < 4; mi++)
#pragma unroll
    for (int ni = 0; ni < 4; ni++) {
      const int n = n0 + wn * 64 + ni * 16 + l15;
      const int nl = n & 255;
      const float bv = bias[nl];
      if (vt) {
        const int m = m0 + wm * 64 + mi * 16 + l4 * 4;
        const int bb = m >> tksh, tt = m & ((1 << tksh) - 1);
        const size_t o = ((((size_t)bb * 8 + (nl >> 5)) * 32 + (nl & 31)) << tksh) + tt;
        unsigned long long wh = 0, wl = 0;
#pragma unroll
        for (int r = 0; r < 4; r++) {
          float v = acc[mi][ni][r] + bv;
          unsigned short hh, ll; split2(v, hh, ll);
          wh |= (unsigned long long)hh << (16 * r);
          wl |= (unsigned long long)ll << (16 * r);
        }
        *(unsigned long long*)(Ch + o) = wh;
        *(unsigned long long*)(Cl + o) = wl;
      } else {
#pragma unroll
        for (int r = 0; r < 4; r++) {
          const int m = m0 + wm * 64 + mi * 16 + l4 * 4 + r;
          float v = acc[mi][ni][r] + bv;
          unsigned short hh, ll; split2(v, hh, ll);
          const size_t o = (size_t)m * 256 + nl;
          Ch[o] = (short)hh; Cl[o] = (short)ll;
        }
      }
    }
}

// ---------------- MFMA fused attention (512 threads, 8 waves) -------------
// Per block: 16 q-rows of one (b,h). Q,K in [b,t,h,d] bf16 hi/lo; V in
// [b,h,d,Tk] bf16 hi/lo. S in LDS fp32, XOR-(row&7) swizzle on 16B groups.
// 1D grid 4096, XCD-aware: n&7 = xcd owns 16 (b,h) groups (K/V L2-resident).
template <int TK>
__global__ __launch_bounds__(512, 4) void attn_mfma(
    const short* __restrict__ Qh, const short* __restrict__ Ql,
    const short* __restrict__ Kh, const short* __restrict__ Kl,
    const short* __restrict__ Vth, const short* __restrict__ Vtl,
    short* __restrict__ Oh, short* __restrict__ Ol,
    float* __restrict__ att_out)
{
  __shared__ float sc[16 * TK];                 // 64KB (TK=1024) / 32KB (512)
  const int n = blockIdx.x;
  const int xcd = n & 7, ii = n >> 3;
  const int bh = xcd * 16 + (ii >> 5);          // [0,128)
  const int q0 = (ii & 31) * 16;
  const int b = bh >> 3, h = bh & 7;
  const int tid = threadIdx.x;
  const int lane = tid & 63, w = tid >> 6;      // 8 waves
  const int l15 = lane & 15, l4 = lane >> 4;
  const float inv_scale = 0.17677669529663687f; // 1/sqrt(32)

  const size_t qbase = (((size_t)b * 512 + q0 + l15) * 8 + h) * 32 + l4 * 8;
  bfrag qh = *(const bfrag*)(Qh + qbase);
  bfrag ql = *(const bfrag*)(Ql + qbase);

  // ---- phase 1: S = QK^T/sqrt(D); wave w covers cols [w*TK/8, +TK/8) -----
#pragma unroll
  for (int t = 0; t < TK / 128; t++) {
    const int n0c = w * (TK / 8) + t * 16;
    const size_t kbase = (((size_t)b * TK + n0c + l15) * 8 + h) * 32 + l4 * 8;
    bfrag kh = *(const bfrag*)(Kh + kbase);
    bfrag kl = *(const bfrag*)(Kl + kbase);
    f32x4 acc = {};
    acc = __builtin_amdgcn_mfma_f32_16x16x32_bf16(qh, kh, acc, 0, 0, 0);
    acc = __builtin_amdgcn_mfma_f32_16x16x32_bf16(qh, kl, acc, 0, 0, 0);
    acc = __builtin_amdgcn_mfma_f32_16x16x32_bf16(ql, kh, acc, 0, 0, 0);
    const int col = n0c + l15;
#pragma unroll
    for (int r = 0; r < 4; r++) {
      const int row = l4 * 4 + r;
      sc[row * TK + ((((col >> 2) ^ (row & 7)) << 2) | (col & 3))] = acc[r] * inv_scale;
    }
  }
  __syncthreads();

  // ---- phase 2: softmax stats (32 thr/row); sc := exp(s-m); inv in reg ---
  const int sr = tid >> 5, sj = tid & 31, srsw = sr & 7;
  float mx = -1e30f;
  for (int k = sj; k < TK; k += 32)
    mx = fmaxf(mx, sc[sr * TK + ((((k >> 2) ^ srsw) << 2) | (k & 3))]);
#pragma unroll
  for (int off = 16; off > 0; off >>= 1) mx = fmaxf(mx, __shfl_xor(mx, off, 32));
  float sum = 0.f;
  for (int k = sj; k < TK; k += 32) {
    const int idx = sr * TK + ((((k >> 2) ^ srsw) << 2) | (k & 3));
    float e = __expf(sc[idx] - mx);
    sc[idx] = e;
    sum += e;
  }
#pragma unroll
  for (int off = 16; off > 0; off >>= 1) sum += __shfl_xor(sum, off, 32);
  const float inv = 1.f / sum;
  __syncthreads();

  // ---- phase 3: att output (normalized on the fly, coalesced float4) -----
  if (att_out) {
    const size_t orow = (((size_t)(b * 8 + h)) * 512 + q0 + sr) * TK;
#pragma unroll
    for (int t = 0; t < TK / 128; t++) {
      const int g = sj + 32 * t;
      float4 e4 = *(const float4*)&sc[sr * TK + ((g ^ srsw) << 2)];
      e4.x *= inv; e4.y *= inv; e4.z *= inv; e4.w *= inv;
      *(float4*)&att_out[orow + g * 4] = e4;
    }
  }

  // ---- phase 4: O = P @ V (unnormalized e; scale by inv at the end) ------
  f32x4 oa0 = {}, oa1 = {};
  const float* pr = sc + l15 * TK;
  const int psw = l15 & 7;
  const size_t vb0 = (((size_t)(b * 8 + h)) * 32 + l15) * TK;
#pragma unroll
  for (int kc = w * (TK / 8); kc < (w + 1) * (TK / 8); kc += 32) {
    const int g0 = (kc >> 2) + l4 * 2;
    float4 p0 = *(const float4*)(pr + ((g0 ^ psw) << 2));
    float4 p1 = *(const float4*)(pr + (((g0 + 1) ^ psw) << 2));
    float f[8] = {p0.x, p0.y, p0.z, p0.w, p1.x, p1.y, p1.z, p1.w};
    uint4v uh, ul;
#pragma unroll
    for (int i = 0; i < 4; i++) {
      unsigned short h0, l0, h1, l1;
      split2(f[2 * i], h0, l0); split2(f[2 * i + 1], h1, l1);
      uh[i] = (unsigned)h0 | ((unsigned)h1 << 16);
      ul[i] = (unsigned)l0 | ((unsigned)l1 << 16);
    }
    bfrag ph = __builtin_bit_cast(bfrag, uh);
    bfrag pl = __builtin_bit_cast(bfrag, ul);
    const size_t vk = vb0 + kc + l4 * 8;
    bfrag v0h = *(const bfrag*)(Vth + vk);
    bfrag v0l = *(const bfrag*)(Vtl + vk);
    bfrag v1h = *(const bfrag*)(Vth + vk + (size_t)16 * TK);
    bfrag v1l = *(const bfrag*)(Vtl + vk + (size_t)16 * TK);
    oa0 = __builtin_amdgcn_mfma_f32_16x16x32_bf16(ph, v0h, oa0, 0, 0, 0);
    oa0 = __builtin_amdgcn_mfma_f32_16x16x32_bf16(ph, v0l, oa0, 0, 0, 0);
    oa0 = __builtin_amdgcn_mfma_f32_16x16x32_bf16(pl, v0h, oa0, 0, 0, 0);
    oa1 = __builtin_amdgcn_mfma_f32_16x16x32_bf16(ph, v1h, oa1, 0, 0, 0);
    oa1 = __builtin_amdgcn_mfma_f32_16x16x32_bf16(ph, v1l, oa1, 0, 0, 0);
    oa1 = __builtin_amdgcn_mfma_f32_16x16x32_bf16(pl, v1h, oa1, 0, 0, 0);
  }
  __syncthreads();               // all reads of sc (P) complete
  float* obuf = sc;              // alias: [8][16] rows x 33-stride partial O
#pragma unroll
  for (int r = 0; r < 4; r++) {
    obuf[(w * 16 + l4 * 4 + r) * 33 + l15]      = oa0[r];
    obuf[(w * 16 + l4 * 4 + r) * 33 + 16 + l15] = oa1[r];
  }
  __syncthreads();
  {  // reduce across 8 waves; thread (q=sr, d=sj) holds inv for row sr
    float s0 = 0.f;
#pragma unroll
    for (int ww = 0; ww < 8; ww++)
      s0 += obuf[(ww * 16 + sr) * 33 + sj];
    s0 *= inv;
    unsigned short h0, l0;
    split2(s0, h0, l0);
    const size_t ob = (((size_t)b * 512 + q0 + sr) * 8 + h) * 32 + sj;
    Oh[ob] = (short)h0;  Ol[ob] = (short)l0;
  }
}

// ---------------- residual + LayerNorm: wave per row, barrier-free --------
template <bool WNORM>
__global__ __launch_bounds__(256) void residual_ln(
    float* __restrict__ x, const float* __restrict__ sub,
    const float* __restrict__ g, const float* __restrict__ bi,
    short* __restrict__ xh, short* __restrict__ xl, float* __restrict__ nrm)
{
  const int wid = threadIdx.x >> 6, lane = threadIdx.x & 63;
  const size_t row = (size_t)blockIdx.x * 4 + wid;
  const int c = lane * 4;
  float4 xv = *(const float4*)&x[row * 256 + c];
  float4 sv = *(const float4*)&sub[row * 256 + c];
  float v0 = xv.x + sv.x, v1 = xv.y + sv.y, v2 = xv.z + sv.z, v3 = xv.w + sv.w;
  float s = v0 + v1 + v2 + v3;
#pragma unroll
  for (int off = 32; off > 0; off >>= 1) s += __shfl_xor(s, off, 64);
  const float mean = s * (1.f / 256.f);
  const float d0 = v0 - mean, d1 = v1 - mean, d2 = v2 - mean, d3 = v3 - mean;
  float s2 = d0 * d0 + d1 * d1 + d2 * d2 + d3 * d3;
#pragma unroll
  for (int off = 32; off > 0; off >>= 1) s2 += __shfl_xor(s2, off, 64);
  const float rs = rsqrtf(s2 * (1.f / 256.f) + 1e-5f);
  const float4 gv = *(const float4*)&g[c];
  const float4 bv = *(const float4*)&bi[c];
  const float y0 = d0 * rs * gv.x + bv.x, y1 = d1 * rs * gv.y + bv.y;
  const float y2 = d2 * rs * gv.z + bv.z, y3 = d3 * rs * gv.w + bv.w;
  float4 yo; yo.x = y0; yo.y = y1; yo.z = y2; yo.w = y3;
  *(float4*)&x[row * 256 + c] = yo;
  ushort4 hh, ll;
  split2(y0, hh.x, ll.x); split2(y1, hh.y, ll.y);
  split2(y2, hh.z, ll.z); split2(y3, hh.w, ll.w);
  *(ushort4*)&xh[row * 256 + c] = hh;
  *(ushort4*)&xl[row * 256 + c] = ll;
  if (WNORM) {
    float ns = y0 * y0 + y1 * y1 + y2 * y2 + y3 * y3;
#pragma unroll
    for (int off = 32; off > 0; off >>= 1) ns += __shfl_xor(ns, off, 64);
    if (lane == 0) nrm[row] = sqrtf(ns);
  }
}

// ---------------- norm-softmax pooling, 2-stage ---------------------------
__global__ __launch_bounds__(256) void pool1(
    const float* __restrict__ x, const float* __restrict__ nrm,
    float* __restrict__ partial)
{
  __shared__ float w[512];
  __shared__ float red[4];
  const int b = blockIdx.x, cchunk = blockIdx.y, tid = threadIdx.x;
  float n0 = nrm[b * 512 + tid], n1 = nrm[b * 512 + 256 + tid];
  float lm = fmaxf(n0, n1);
  for (int off = 32; off > 0; off >>= 1) lm = fmaxf(lm, __shfl_xor(lm, off, 64));
  if ((tid & 63) == 0) red[tid >> 6] = lm;
  __syncthreads();
  float m = fmaxf(fmaxf(red[0], red[1]), fmaxf(red[2], red[3]));
  float e0 = __expf(n0 - m), e1 = __expf(n1 - m);
  float ls = e0 + e1;
  for (int off = 32; off > 0; off >>= 1) ls += __shfl_xor(ls, off, 64);
  __syncthreads();
  if ((tid & 63) == 0) red[tid >> 6] = ls;
  __syncthreads();
  float inv = 1.f / (red[0] + red[1] + red[2] + red[3]);
  w[tid] = e0 * inv; w[tid + 256] = e1 * inv;
  __syncthreads();
  float acc = 0.f;
  const int t0 = cchunk * 128;
  for (int t = t0; t < t0 + 128; t++)
    acc += w[t] * x[((size_t)b * 512 + t) * 256 + tid];
  partial[((size_t)b * 4 + cchunk) * 256 + tid] = acc;
}

__global__ __launch_bounds__(256) void pool2(
    const float* __restrict__ partial, float* __restrict__ pooled,
    float* __restrict__ pooled_out)
{
  const int b = blockIdx.x, tid = threadIdx.x;
  float s = partial[((size_t)b * 4 + 0) * 256 + tid]
          + partial[((size_t)b * 4 + 1) * 256 + tid]
          + partial[((size_t)b * 4 + 2) * 256 + tid]
          + partial[((size_t)b * 4 + 3) * 256 + tid];
  pooled[b * 256 + tid] = s;
  pooled_out[b * 256 + tid] = s;
}

// ---------------- FC head (one block per batch) ----------------------------
__global__ __launch_bounds__(256) void fc_head(
    const float* __restrict__ pooled,
    const float* __restrict__ fc1_w, const float* __restrict__ fc1_b,
    const float* __restrict__ fc2_w, const float* __restrict__ fc2_b,
    float* __restrict__ label_out)
{
  __shared__ float pl[256];
  __shared__ float hid[256];
  const int b = blockIdx.x, tid = threadIdx.x;
  pl[tid] = pooled[b * 256 + tid];
  __syncthreads();
  float acc = fc1_b[tid];
  for (int k = 0; k < 256; k++)
    acc += pl[k] * fc1_w[k * 256 + tid];
  hid[tid] = fmaxf(acc, 0.f);
  __syncthreads();
  if (tid < 2) {
    float s = fc2_b[tid];
    for (int k = 0; k < 256; k++)
      s += hid[k] * fc2_w[k * 2 + tid];
    label_out[b * 2 + tid] = s;
  }
}

extern "C" void kernel_launch(void* const* d_in, const int* in_sizes, int n_in,
                              void* d_out, int out_size, void* d_ws, size_t ws_size,
                              hipStream_t stream)
{
  const float* trg   = (const float*)d_in[0];
  const float* src   = (const float*)d_in[1];
  const float* ft_w  = (const float*)d_in[2];
  const float* ft_b  = (const float*)d_in[3];
  const float* fc1_w = (const float*)d_in[4];
  const float* fc1_b = (const float*)d_in[5];
  const float* fc2_w = (const float*)d_in[6];
  const float* fc2_b = (const float*)d_in[7];
  const float* ln_g  = (const float*)d_in[8];
  const float* ln_b  = (const float*)d_in[9];
  const float* pf_w1 = (const float*)d_in[10];
  const float* pf_b1 = (const float*)d_in[11];
  const float* pf_w2 = (const float*)d_in[12];
  const float* pf_b2 = (const float*)d_in[13];
  const float* aw[2][8];
  for (int p = 0; p < 2; p++)
    for (int i = 0; i < 8; i++) aw[p][i] = (const float*)d_in[14 + p * 8 + i];
  float* outp = (float*)d_out;

  char* wsb = (char*)d_ws;
  const size_t MB = 1u << 20;
  float* x    = (float*)(wsb);
  float* sub  = (float*)(wsb + 8 * MB);
  short* x_hi = (short*)(wsb + 16 * MB);
  short* x_lo = (short*)(wsb + 20 * MB);
  short* qbh  = (short*)(wsb + 24 * MB);
  short* qbl  = (short*)(wsb + 28 * MB);
  short* kbh  = (short*)(wsb + 32 * MB);
  short* kbl  = (short*)(wsb + 40 * MB);
  short* vth  = (short*)(wsb + 48 * MB);
  short* vtl  = (short*)(wsb + 56 * MB);
  short* obh  = (short*)(wsb + 64 * MB);
  short* obl  = (short*)(wsb + 68 * MB);
  short* srch = (short*)(wsb + 72 * MB);
  short* srcl = (short*)(wsb + 80 * MB);
  short* w_hi = (short*)(wsb + 88 * MB);
  short* w_lo = (short*)(wsb + 92 * MB);
  // aliases with disjoint lifetimes:
  short* ffmh = kbh;                 // FFN mid hi (kb dead during FFN)
  short* ffml = kbl;
  short* trgh = vth;                 // pre-loop only
  short* trgl = vtl;
  float* nrm  = (float*)qbh;         // post-loop only (32KB)
  float* pld  = (float*)qbh + 8192;  // 16KB
  float* part = (float*)qbh + 16384; // 64KB

  // weight transposed-split offsets (elems): ftT then per-layer
  auto woff = [](int l, int idx) -> size_t {
    size_t base = 16384 + (size_t)l * 786432;
    if (idx < 8)  return base + (size_t)idx * 65536;
    if (idx == 8) return base + 524288;
    return base + 655360;
  };

  // ---- one-time prep: split all weights (one launch) + inputs ----
  {
    WAll P{};
    int t = 0, e = 0;
    auto add = [&](const float* s, int K, int N, size_t dst) {
      P.d[e].src = s; P.d[e].dst = (long long)dst;
      P.d[e].K = K; P.d[e].N = N; P.d[e].tile0 = t;
      t += (K / 32) * (N / 32); e++;
    };
    add(ft_w, 64, 256, 0);
    for (int l = 0; l < 2; l++) {
      const size_t wo = (size_t)l * 65536;
      for (int i = 0; i < 4; i++) add(aw[0][2 * i] + wo, 256, 256, woff(l, i));
      for (int i = 0; i < 4; i++) add(aw[1][2 * i] + wo, 256, 256, woff(l, 4 + i));
      add(pf_w1 + (size_t)l * 131072, 256, 512, woff(l, 8));
      add(pf_w2 + (size_t)l * 131072, 512, 256, woff(l, 9));
    }
    wsplit_all<<<t, 256, 0, stream>>>(P, w_hi, w_lo);
  }
  xsplit<<<512, 256, 0, stream>>>(trg, trgh, trgl, 131072);
  xsplit<<<4096, 256, 0, stream>>>(src, srch, srcl, 1048576);

  // feature transform: x = trg @ ft_w + ft_b  (also emits x hi/lo)
  gemm_mfma<false, true, true><<<dim3(64, 2), 256, 0, stream>>>(
      trgh, trgl, w_hi, w_lo, ft_b, x, x_hi, x_lo, 8192, 256, 64);

  for (int l = 0; l < 2; l++) {
    const size_t bo = (size_t)l * 256;
    // ---- self attention: fused QKV projection (1 launch) ----
    gemm_qkv<<<dim3(64, 6), 256, 0, stream>>>(
        x_hi, x_lo, w_hi + woff(l, 0), w_lo + woff(l, 0),
        aw[0][1] + bo, aw[0][3] + bo, aw[0][5] + bo,
        qbh, qbl, kbh, kbl, vth, vtl, 8192, 256, 9, 3);
    attn_mfma<512><<<4096, 512, 0, stream>>>(
        qbh, qbl, kbh, kbl, vth, vtl, obh, obl, (float*)nullptr);
    gemm_mfma<false, false, true><<<dim3(64, 2), 256, 0, stream>>>(
        obh, obl, w_hi + woff(l, 3), w_lo + woff(l, 3), aw[0][7] + bo,
        sub, nullptr, nullptr, 8192, 256, 256);
    residual_ln<false><<<2048, 256, 0, stream>>>(x, sub, ln_g + bo, ln_b + bo,
                                                 x_hi, x_lo, nullptr);
    // ---- encoder (cross) attention: Q from x; fused KV from src ----
    gemm_mfma<false, true, false><<<dim3(64, 2), 256, 0, stream>>>(
        x_hi, x_lo, w_hi + woff(l, 4), w_lo + woff(l, 4), aw[1][1] + bo,
        nullptr, qbh, qbl, 8192, 256, 256);
    gemm_qkv<<<dim3(128, 4), 256, 0, stream>>>(
        srch, srcl, w_hi + woff(l, 5), w_lo + woff(l, 5),
        aw[1][3] + bo, aw[1][5] + bo, nullptr,
        kbh, kbl, vth, vtl, nullptr, nullptr, 16384, 256, 10, 2);
    {
      float* att = (l == 1) ? (outp + 4128) : (float*)nullptr;
      attn_mfma<1024><<<4096, 512, 0, stream>>>(
          qbh, qbl, kbh, kbl, vth, vtl, obh, obl, att);
    }
    gemm_mfma<false, false, true><<<dim3(64, 2), 256, 0, stream>>>(
        obh, obl, w_hi + woff(l, 7), w_lo + woff(l, 7), aw[1][7] + bo,
        sub, nullptr, nullptr, 8192, 256, 256);
    residual_ln<false><<<2048, 256, 0, stream>>>(x, sub, ln_g + bo, ln_b + bo,
                                                 x_hi, x_lo, nullptr);
    // ---- feed forward ----
    gemm_mfma<true, true, false><<<dim3(64, 4), 256, 0, stream>>>(
        x_hi, x_lo, w_hi + woff(l, 8), w_lo + woff(l, 8), pf_b1 + (size_t)l * 512,
        nullptr, ffmh, ffml, 8192, 512, 256);
    gemm_mfma<false, false, true><<<dim3(64, 2), 256, 0, stream>>>(
        ffmh, ffml, w_hi + woff(l, 9), w_lo + woff(l, 9), pf_b2 + bo,
        sub, nullptr, nullptr, 8192, 256, 512);
    if (l == 0) {
      residual_ln<false><<<2048, 256, 0, stream>>>(x, sub, ln_g + bo, ln_b + bo,
                                                   x_hi, x_lo, nullptr);
    } else {
      residual_ln<true><<<2048, 256, 0, stream>>>(x, sub, ln_g + bo, ln_b + bo,
                                                  x_hi, x_lo, nrm);
    }
  }

  // ---- pooling + head ----
  pool1<<<dim3(16, 4), 256, 0, stream>>>(x, nrm, part);
  pool2<<<16, 256, 0, stream>>>(part, pld, outp + 32);
  fc_head<<<16, 256, 0, stream>>>(pld, fc1_w, fc1_b, fc2_w, fc2_b, outp);
}